// Round 7
// baseline (1349.663 us; speedup 1.0000x reference)
//
#include <hip/hip_runtime.h>
#include <math.h>

#define N_NODES 65536
#define F_DIM 512
#define H_DIM 256
#define E_EDGES 1048576
#define R_REPS 512

__device__ __forceinline__ float selu_f(float x) {
    const float SC = 1.0507009873554804934f;
    const float AL = 1.6732632423543772848f;
    return x > 0.f ? SC * x : SC * AL * expm1f(x);
}

__global__ void k_init(int* cnt_s, int* cnt_r, int* cursor, float* colsum,
                       unsigned* node_min, unsigned long long* center_min,
                       double* loss_acc) {
    int i = blockIdx.x * 256 + threadIdx.x;
    if (i < N_NODES) { cnt_s[i] = 0; cnt_r[i] = 0; cursor[i] = 0; node_min[i] = 0x7F800000u; }
    if (i < H_DIM) colsum[i] = 0.f;
    if (i < R_REPS) center_min[i] = ~0ull;
    if (i == 0) *loss_acc = 0.0;
}

__global__ void k_degree(const int* __restrict__ senders, const int* __restrict__ receivers,
                         int* __restrict__ cnt_s, int* __restrict__ cnt_r) {
    int e = blockIdx.x * 256 + threadIdx.x;
    if (e < E_EDGES) {
        atomicAdd(&cnt_s[senders[e]], 1);
        atomicAdd(&cnt_r[receivers[e]], 1);
    }
}

__global__ void k_invsqrt(const int* __restrict__ cnt_s, const int* __restrict__ cnt_r,
                          float* __restrict__ inv_s, float* __restrict__ inv_r) {
    int i = blockIdx.x * 256 + threadIdx.x;
    if (i < N_NODES) {
        inv_s[i] = 1.0f / sqrtf(fmaxf((float)cnt_s[i], 1.f));
        inv_r[i] = 1.0f / sqrtf(fmaxf((float)cnt_r[i], 1.f));
    }
}

// single-block hierarchical exclusive scan of cnt_r[65536] -> row_ptr[65537]
__global__ __launch_bounds__(1024) void k_scan(const int* __restrict__ cnt,
                                               int* __restrict__ row_ptr) {
    __shared__ int part[1024];
    int t = threadIdx.x;
    int base = t * 64;
    int s = 0;
    #pragma unroll 8
    for (int i = 0; i < 64; ++i) s += cnt[base + i];
    part[t] = s;
    __syncthreads();
    for (int off = 1; off < 1024; off <<= 1) {
        int other = (t >= off) ? part[t - off] : 0;
        __syncthreads();
        part[t] += other;
        __syncthreads();
    }
    int run = part[t] - s;
    for (int i = 0; i < 64; ++i) {
        row_ptr[base + i] = run;
        run += cnt[base + i];
    }
    if (t == 1023) row_ptr[N_NODES] = run;
}

__global__ void k_fill(const int* __restrict__ senders, const int* __restrict__ receivers,
                       const int* __restrict__ row_ptr, int* __restrict__ cursor,
                       int* __restrict__ csr_send) {
    int e = blockIdx.x * 256 + threadIdx.x;
    if (e < E_EDGES) {
        int r = receivers[e];
        int pos = atomicAdd(&cursor[r], 1);
        csr_send[row_ptr[r] + pos] = senders[e];
    }
}

// ---- 256x128 tile, 16x8 microtile machinery ----
#define ROWFMA(r, s) \
    acc[r][0].x += (s)*bv0.x; acc[r][0].y += (s)*bv0.y; acc[r][0].z += (s)*bv0.z; acc[r][0].w += (s)*bv0.w; \
    acc[r][1].x += (s)*bv1.x; acc[r][1].y += (s)*bv1.y; acc[r][1].z += (s)*bv1.z; acc[r][1].w += (s)*bv1.w;

#define STAGE_A(q) \
    As[q][ 0][t]=a0.x; As[q][ 1][t]=a0.y; As[q][ 2][t]=a0.z; As[q][ 3][t]=a0.w; \
    As[q][ 4][t]=a1.x; As[q][ 5][t]=a1.y; As[q][ 6][t]=a1.z; As[q][ 7][t]=a1.w; \
    As[q][ 8][t]=a2.x; As[q][ 9][t]=a2.y; As[q][10][t]=a2.z; As[q][11][t]=a2.w; \
    As[q][12][t]=a3.x; As[q][13][t]=a3.y; As[q][14][t]=a3.z; As[q][15][t]=a3.w;

#define COMPUTE_STEP(p) \
    _Pragma("unroll") \
    for (int k = 0; k < 16; ++k) { \
        float4 bv0 = *(float4*)&Bs[p][k][ng << 2]; \
        float4 bv1 = *(float4*)&Bs[p][k][64 + (ng << 2)]; \
        _Pragma("unroll") \
        for (int i = 0; i < 4; ++i) { \
            float4 av = *(float4*)&As[p][k][(mg << 4) + (i << 2)]; \
            ROWFMA((i<<2)+0, av.x) ROWFMA((i<<2)+1, av.y) \
            ROWFMA((i<<2)+2, av.z) ROWFMA((i<<2)+3, av.w) \
        } \
    }

// X = (A @ W + b) * inv_s[row]; dbuf LDS, 1 barrier/iter, loads-early/write-late
__global__ __launch_bounds__(256) void k_gemm256(
    const float* __restrict__ A, const float* __restrict__ W,
    const float* __restrict__ bias, const float* __restrict__ inv_s,
    float* __restrict__ X) {
    __shared__ float As[2][16][260];
    __shared__ float Bs[2][16][132];
    const int t = threadIdx.x;
    const int mg = t >> 4;            // 0..15, 16 rows each
    const int ng = t & 15;            // 0..15, cols ng*4 and ng*4+64
    const int m0 = blockIdx.x * 256;
    const int n0 = blockIdx.y * 128;
    const int bk = t >> 4;            // 0..15 W-row in k-step
    const int bn = (t & 15) << 3;     // 0..120
    const float* Arow = A + (size_t)(m0 + t) * F_DIM;
    const float* Wrow = W + (size_t)bk * H_DIM + n0 + bn;
    float4 acc[16][2] = {};
    {   // prologue: stage buf 0
        float4 a0 = *(const float4*)&Arow[0];
        float4 a1 = *(const float4*)&Arow[4];
        float4 a2 = *(const float4*)&Arow[8];
        float4 a3 = *(const float4*)&Arow[12];
        float4 b0 = *(const float4*)&Wrow[0];
        float4 b1 = *(const float4*)&Wrow[4];
        STAGE_A(0)
        *(float4*)&Bs[0][bk][bn] = b0;
        *(float4*)&Bs[0][bk][bn + 4] = b1;
    }
    int p = 0;
    for (int k0 = 0; k0 < F_DIM; k0 += 16) {
        __syncthreads();
        float4 a0, a1, a2, a3, b0, b1;
        const bool more = (k0 + 16) < F_DIM;
        if (more) {   // issue next-tile loads; land under the FMA burst
            a0 = *(const float4*)&Arow[k0 + 16];
            a1 = *(const float4*)&Arow[k0 + 20];
            a2 = *(const float4*)&Arow[k0 + 24];
            a3 = *(const float4*)&Arow[k0 + 28];
            b0 = *(const float4*)&Wrow[(size_t)(k0 + 16) * H_DIM];
            b1 = *(const float4*)&Wrow[(size_t)(k0 + 16) * H_DIM + 4];
        }
        COMPUTE_STEP(p)
        if (more) {
            int q = p ^ 1;
            STAGE_A(q)
            *(float4*)&Bs[q][bk][bn] = b0;
            *(float4*)&Bs[q][bk][bn + 4] = b1;
        }
        p ^= 1;
    }
    float4 bb0 = *(const float4*)&bias[n0 + (ng << 2)];
    float4 bb1 = *(const float4*)&bias[n0 + 64 + (ng << 2)];
    #pragma unroll
    for (int r = 0; r < 16; ++r) {
        int row = m0 + (mg << 4) + r;
        float w = inv_s[row];
        float4 o0, o1;
        o0.x = (acc[r][0].x + bb0.x) * w; o0.y = (acc[r][0].y + bb0.y) * w;
        o0.z = (acc[r][0].z + bb0.z) * w; o0.w = (acc[r][0].w + bb0.w) * w;
        o1.x = (acc[r][1].x + bb1.x) * w; o1.y = (acc[r][1].y + bb1.y) * w;
        o1.z = (acc[r][1].z + bb1.z) * w; o1.w = (acc[r][1].w + bb1.w) * w;
        *(float4*)&X[(size_t)row * H_DIM + n0 + (ng << 2)] = o0;
        *(float4*)&X[(size_t)row * H_DIM + n0 + 64 + (ng << 2)] = o1;
    }
}

// one wave per node: acc = sum over incident edges of X[sender]; fused *inv_r + selu
__global__ __launch_bounds__(256) void k_agg1(
    const float* __restrict__ X, const int* __restrict__ csr_send,
    const int* __restrict__ row_ptr, const float* __restrict__ inv_r,
    float* __restrict__ out_emb) {
    int node = blockIdx.x * 4 + (threadIdx.x >> 6);
    int lane = threadIdx.x & 63;
    int beg = row_ptr[node], end = row_ptr[node + 1];
    float4 acc = {0.f, 0.f, 0.f, 0.f};
    for (int b = beg; b < end; b += 64) {
        int n = min(64, end - b);
        int myS = (lane < n) ? csr_send[b + lane] : 0;
        for (int i = 0; i < n; ++i) {
            int s = __shfl(myS, i);
            float4 x = *(const float4*)&X[(size_t)s * H_DIM + (lane << 2)];
            acc.x += x.x; acc.y += x.y; acc.z += x.z; acc.w += x.w;
        }
    }
    float ir = inv_r[node];
    float4 o;
    o.x = selu_f(acc.x * ir);
    o.y = selu_f(acc.y * ir);
    o.z = selu_f(acc.z * ir);
    o.w = selu_f(acc.w * ir);
    *(float4*)&out_emb[(size_t)node * H_DIM + (lane << 2)] = o;
}

// GCN2: aggregate + *inv_r + selu + dot(v) fused; nodes2 never materialized
__global__ __launch_bounds__(256) void k_agg2(
    const float* __restrict__ X, const int* __restrict__ csr_send,
    const int* __restrict__ row_ptr, const float* __restrict__ inv_r,
    const float* __restrict__ v, float* __restrict__ out) {
    int node = blockIdx.x * 4 + (threadIdx.x >> 6);
    int lane = threadIdx.x & 63;
    int beg = row_ptr[node], end = row_ptr[node + 1];
    float4 acc = {0.f, 0.f, 0.f, 0.f};
    for (int b = beg; b < end; b += 64) {
        int n = min(64, end - b);
        int myS = (lane < n) ? csr_send[b + lane] : 0;
        for (int i = 0; i < n; ++i) {
            int s = __shfl(myS, i);
            float4 x = *(const float4*)&X[(size_t)s * H_DIM + (lane << 2)];
            acc.x += x.x; acc.y += x.y; acc.z += x.z; acc.w += x.w;
        }
    }
    float ir = inv_r[node];
    float4 vv = *(const float4*)&v[lane << 2];
    float d = selu_f(acc.x * ir) * vv.x + selu_f(acc.y * ir) * vv.y
            + selu_f(acc.z * ir) * vv.z + selu_f(acc.w * ir) * vv.w;
    #pragma unroll
    for (int off = 32; off; off >>= 1) d += __shfl_down(d, off);
    if (lane == 0) out[node] = d;
}

__global__ __launch_bounds__(256) void k_colsum(const float* __restrict__ nodes1,
                                                float* __restrict__ colsum) {
    int t = threadIdx.x;
    size_t r0 = (size_t)blockIdx.x * 64;
    float s = 0.f;
    for (int r = 0; r < 64; ++r) s += nodes1[(r0 + r) * H_DIM + t];
    atomicAdd(&colsum[t], s);
}

__global__ void k_summary_v(const float* __restrict__ colsum, const float* __restrict__ Wb,
                            float* __restrict__ v) {
    __shared__ float s_sum[H_DIM];
    int t = threadIdx.x;
    float m = colsum[t] * (1.f / (float)N_NODES);
    s_sum[t] = 1.f / (1.f + expf(-m));
    __syncthreads();
    float acc = 0.f;
    for (int j = 0; j < H_DIM; ++j) acc += Wb[t * H_DIM + j] * s_sum[j];
    v[t] = acc;
}

// fused: logits[row]=dot(emb_row, v) (pre-norm), then row-normalize in place + e2
__global__ __launch_bounds__(256) void k_normrow(
    float* __restrict__ emb, const float* __restrict__ v,
    float* __restrict__ logits, float* __restrict__ e2) {
    int row = blockIdx.x * 4 + (threadIdx.x >> 6);
    int lane = threadIdx.x & 63;
    float4 a = *(float4*)&emb[(size_t)row * H_DIM + (lane << 2)];
    float4 vv = *(const float4*)&v[lane << 2];
    float d = a.x * vv.x + a.y * vv.y + a.z * vv.z + a.w * vv.w;
    float ss = a.x * a.x + a.y * a.y + a.z * a.z + a.w * a.w;
    #pragma unroll
    for (int off = 32; off; off >>= 1) {
        d += __shfl_xor(d, off);
        ss += __shfl_xor(ss, off);
    }
    if (lane == 0) logits[row] = d;
    float inv = 1.f / sqrtf(ss);
    a.x *= inv; a.y *= inv; a.z *= inv; a.w *= inv;
    *(float4*)&emb[(size_t)row * H_DIM + (lane << 2)] = a;
    float s2 = a.x * a.x + a.y * a.y + a.z * a.z + a.w * a.w;
    #pragma unroll
    for (int off = 32; off; off >>= 1) s2 += __shfl_xor(s2, off);
    if (lane == 0) e2[row] = s2;
}

__global__ __launch_bounds__(256) void k_c2(const float* __restrict__ centers,
                                            float* __restrict__ c2) {
    int row = blockIdx.x * 4 + (threadIdx.x >> 6);
    int lane = threadIdx.x & 63;
    float4 a = *(const float4*)&centers[(size_t)row * H_DIM + (lane << 2)];
    float ss = a.x * a.x + a.y * a.y + a.z * a.z + a.w * a.w;
    #pragma unroll
    for (int off = 32; off; off >>= 1) ss += __shfl_xor(ss, off);
    if (lane == 0) c2[row] = ss;
}

#define DC(r, jh, comp, jidx) { \
    float d2_ = ev + c2v##jh.comp - 2.f * acc[r][jh].comp; \
    float d_ = sqrtf(fmaxf(d2_, 1e-12f)); \
    rmin = fminf(rmin, d_); \
    unsigned long long pk_ = ((unsigned long long)__float_as_uint(d_) << 32) | (unsigned)row; \
    if (pk_ < cb[jh][jidx]) cb[jh][jidx] = pk_; }
#define DROW(r) \
    DC(r, 0, x, 0) DC(r, 0, y, 1) DC(r, 0, z, 2) DC(r, 0, w, 3) \
    DC(r, 1, x, 0) DC(r, 1, y, 1) DC(r, 1, z, 2) DC(r, 1, w, 3)

// fused emb @ centers^T + min/argmin; 256x128 tile, 16x8 microtile, dbuf
__global__ __launch_bounds__(256) void k_cluster256(
    const float* __restrict__ emb, const float* __restrict__ centers,
    const float* __restrict__ e2, const float* __restrict__ c2,
    unsigned* __restrict__ node_min, unsigned long long* __restrict__ center_min) {
    __shared__ float As[2][16][260];
    __shared__ float Bs[2][16][132];
    __shared__ unsigned s_nmin[256];
    __shared__ unsigned long long s_cmin[128];
    const int t = threadIdx.x;
    const int mg = t >> 4;
    const int ng = t & 15;
    const int m0 = blockIdx.x * 256;
    const int n0 = blockIdx.y * 128;
    const int cn = t >> 1;            // 0..127 center within tile
    const int ck = (t & 1) << 3;      // 0 or 8
    const float* Arow = emb + (size_t)(m0 + t) * H_DIM;
    const float* Crow = centers + (size_t)(n0 + cn) * H_DIM + ck;
    float4 acc[16][2] = {};
    s_nmin[t] = 0x7F800000u;
    if (t < 128) s_cmin[t] = ~0ull;
    {   // prologue: stage buf 0
        float4 a0 = *(const float4*)&Arow[0];
        float4 a1 = *(const float4*)&Arow[4];
        float4 a2 = *(const float4*)&Arow[8];
        float4 a3 = *(const float4*)&Arow[12];
        float4 b0 = *(const float4*)&Crow[0];
        float4 b1 = *(const float4*)&Crow[4];
        STAGE_A(0)
        Bs[0][ck + 0][cn] = b0.x; Bs[0][ck + 1][cn] = b0.y;
        Bs[0][ck + 2][cn] = b0.z; Bs[0][ck + 3][cn] = b0.w;
        Bs[0][ck + 4][cn] = b1.x; Bs[0][ck + 5][cn] = b1.y;
        Bs[0][ck + 6][cn] = b1.z; Bs[0][ck + 7][cn] = b1.w;
    }
    int p = 0;
    for (int k0 = 0; k0 < H_DIM; k0 += 16) {
        __syncthreads();
        float4 a0, a1, a2, a3, b0, b1;
        const bool more = (k0 + 16) < H_DIM;
        if (more) {
            a0 = *(const float4*)&Arow[k0 + 16];
            a1 = *(const float4*)&Arow[k0 + 20];
            a2 = *(const float4*)&Arow[k0 + 24];
            a3 = *(const float4*)&Arow[k0 + 28];
            b0 = *(const float4*)&Crow[k0 + 16];
            b1 = *(const float4*)&Crow[k0 + 20];
        }
        COMPUTE_STEP(p)
        if (more) {
            int q = p ^ 1;
            STAGE_A(q)
            Bs[q][ck + 0][cn] = b0.x; Bs[q][ck + 1][cn] = b0.y;
            Bs[q][ck + 2][cn] = b0.z; Bs[q][ck + 3][cn] = b0.w;
            Bs[q][ck + 4][cn] = b1.x; Bs[q][ck + 5][cn] = b1.y;
            Bs[q][ck + 6][cn] = b1.z; Bs[q][ck + 7][cn] = b1.w;
        }
        p ^= 1;
    }
    float4 c2v0 = *(const float4*)&c2[n0 + (ng << 2)];
    float4 c2v1 = *(const float4*)&c2[n0 + 64 + (ng << 2)];
    unsigned long long cb[2][4] = {{~0ull, ~0ull, ~0ull, ~0ull}, {~0ull, ~0ull, ~0ull, ~0ull}};
    #pragma unroll
    for (int r = 0; r < 16; ++r) {
        int row = m0 + (mg << 4) + r;
        float ev = e2[row];
        float rmin = 3.402823466e+38f;
        DROW(r)
        atomicMin(&s_nmin[(mg << 4) + r], __float_as_uint(rmin));
    }
    #pragma unroll
    for (int jh = 0; jh < 2; ++jh)
        #pragma unroll
        for (int j = 0; j < 4; ++j)
            atomicMin(&s_cmin[jh * 64 + (ng << 2) + j], cb[jh][j]);
    __syncthreads();
    atomicMin(&node_min[m0 + t], s_nmin[t]);
    if (t < 128) atomicMin(&center_min[n0 + t], s_cmin[t]);
}

__global__ __launch_bounds__(256) void k_loss(const unsigned* __restrict__ node_min,
                                              double* __restrict__ acc) {
    int i = blockIdx.x * 256 + threadIdx.x;
    float s = __uint_as_float(node_min[i]);
    #pragma unroll
    for (int off = 32; off; off >>= 1) s += __shfl_down(s, off);
    __shared__ float ws[4];
    int lane = threadIdx.x & 63, w = threadIdx.x >> 6;
    if (lane == 0) ws[w] = s;
    __syncthreads();
    if (threadIdx.x == 0) {
        float tot = ws[0] + ws[1] + ws[2] + ws[3];
        atomicAdd(acc, (double)tot);
    }
}

__global__ void k_finalize(const unsigned long long* __restrict__ center_min,
                           const double* __restrict__ loss_acc,
                           float* __restrict__ rep_out, float* __restrict__ loss_out) {
    int t = blockIdx.x * 256 + threadIdx.x;
    if (t < R_REPS) rep_out[t] = (float)(unsigned)(center_min[t] & 0xFFFFFFFFull);
    if (t == 0) *loss_out = (float)(*loss_acc);
}

extern "C" void kernel_launch(void* const* d_in, const int* in_sizes, int n_in,
                              void* d_out, int out_size, void* d_ws, size_t ws_size,
                              hipStream_t stream) {
    const float* nodes   = (const float*)d_in[0];
    const float* c_nodes = (const float*)d_in[1];
    const int* senders   = (const int*)d_in[2];
    const int* receivers = (const int*)d_in[3];
    const float* W       = (const float*)d_in[4];
    const float* bias    = (const float*)d_in[5];
    const float* Wb      = (const float*)d_in[6];
    const float* centers = (const float*)d_in[7];

    float* out = (float*)d_out;
    float* out_emb    = out;                                  // N*H
    float* out_cent   = out + (size_t)N_NODES * H_DIM;        // R*H
    float* out_rep    = out_cent + (size_t)R_REPS * H_DIM;    // R
    float* out_loss   = out_rep + R_REPS;                     // 1
    float* out_logits = out_loss + 1;                         // 2N

    // ---- workspace: 8-byte-typed scratch first (alignment), then 4-byte arrays ----
    char* wp = (char*)d_ws;
    unsigned long long* center_min = (unsigned long long*)wp; wp += (size_t)R_REPS * 8;
    double* loss_acc = (double*)wp;             wp += 8;
    float* X = (float*)wp;                      wp += (size_t)N_NODES * H_DIM * 4;
    int* csr_send = (int*)wp;                   wp += (size_t)E_EDGES * 4;
    int* row_ptr = (int*)wp;                    wp += (size_t)(N_NODES + 2) * 4;
    int* cursor = (int*)wp;                     wp += (size_t)N_NODES * 4;
    int* cnt_s = (int*)wp;                      wp += (size_t)N_NODES * 4;
    int* cnt_r = (int*)wp;                      wp += (size_t)N_NODES * 4;
    float* inv_s = (float*)wp;                  wp += (size_t)N_NODES * 4;
    float* inv_r = (float*)wp;                  wp += (size_t)N_NODES * 4;
    float* colsum = (float*)wp;                 wp += (size_t)H_DIM * 4;
    float* v = (float*)wp;                      wp += (size_t)H_DIM * 4;
    float* e2 = (float*)wp;                     wp += (size_t)N_NODES * 4;
    float* c2 = (float*)wp;                     wp += (size_t)R_REPS * 4;
    unsigned* node_min = (unsigned*)wp;         wp += (size_t)N_NODES * 4;

    k_init<<<N_NODES / 256, 256, 0, stream>>>(cnt_s, cnt_r, cursor, colsum, node_min, center_min, loss_acc);
    k_degree<<<E_EDGES / 256, 256, 0, stream>>>(senders, receivers, cnt_s, cnt_r);
    k_invsqrt<<<N_NODES / 256, 256, 0, stream>>>(cnt_s, cnt_r, inv_s, inv_r);
    k_scan<<<1, 1024, 0, stream>>>(cnt_r, row_ptr);
    k_fill<<<E_EDGES / 256, 256, 0, stream>>>(senders, receivers, row_ptr, cursor, csr_send);

    dim3 gg(N_NODES / 256, H_DIM / 128);
    // GCN1
    k_gemm256<<<gg, 256, 0, stream>>>(nodes, W, bias, inv_s, X);
    k_agg1<<<N_NODES / 4, 256, 0, stream>>>(X, csr_send, row_ptr, inv_r, out_emb);

    k_colsum<<<N_NODES / 64, 256, 0, stream>>>(out_emb, colsum);
    k_summary_v<<<1, 256, 0, stream>>>(colsum, Wb, v);
    k_normrow<<<N_NODES / 4, 256, 0, stream>>>(out_emb, v, out_logits, e2);
    k_c2<<<R_REPS / 4, 256, 0, stream>>>(centers, c2);

    dim3 gc(N_NODES / 256, R_REPS / 128);
    k_cluster256<<<gc, 256, 0, stream>>>(out_emb, centers, e2, c2, node_min, center_min);
    k_loss<<<N_NODES / 256, 256, 0, stream>>>(node_min, loss_acc);
    k_finalize<<<2, 256, 0, stream>>>(center_min, loss_acc, out_rep, out_loss);
    hipMemcpyAsync(out_cent, centers, (size_t)R_REPS * H_DIM * 4, hipMemcpyDeviceToDevice, stream);

    // GCN2 (reuse X; nodes2 never materialized)
    k_gemm256<<<gg, 256, 0, stream>>>(c_nodes, W, bias, inv_s, X);
    k_agg2<<<N_NODES / 4, 256, 0, stream>>>(X, csr_send, row_ptr, inv_r, v, out_logits + N_NODES);
}

// Round 8
// 1000.335 us; speedup vs baseline: 1.3492x; 1.3492x over previous
//
#include <hip/hip_runtime.h>
#include <math.h>

#define N_NODES 65536
#define F_DIM 512
#define H_DIM 256
#define E_EDGES 1048576
#define R_REPS 512

typedef _Float16 f16x8 __attribute__((ext_vector_type(8)));
typedef _Float16 f16x4 __attribute__((ext_vector_type(4)));
typedef float f32x4_t __attribute__((ext_vector_type(4)));

__device__ __forceinline__ float selu_f(float x) {
    const float SC = 1.0507009873554804934f;
    const float AL = 1.6732632423543772848f;
    return x > 0.f ? SC * x : SC * AL * expm1f(x);
}

__global__ void k_init(int* cnt_s, int* cnt_r, int* cursor, float* colsum,
                       unsigned* node_min, unsigned long long* center_min,
                       double* loss_acc) {
    int i = blockIdx.x * 256 + threadIdx.x;
    if (i < N_NODES) { cnt_s[i] = 0; cnt_r[i] = 0; cursor[i] = 0; node_min[i] = 0x7F800000u; }
    if (i < H_DIM) colsum[i] = 0.f;
    if (i < R_REPS) center_min[i] = ~0ull;
    if (i == 0) *loss_acc = 0.0;
}

__global__ void k_degree(const int* __restrict__ senders, const int* __restrict__ receivers,
                         int* __restrict__ cnt_s, int* __restrict__ cnt_r) {
    int e = blockIdx.x * 256 + threadIdx.x;
    if (e < E_EDGES) {
        atomicAdd(&cnt_s[senders[e]], 1);
        atomicAdd(&cnt_r[receivers[e]], 1);
    }
}

__global__ void k_invsqrt(const int* __restrict__ cnt_s, const int* __restrict__ cnt_r,
                          float* __restrict__ inv_s, float* __restrict__ inv_r) {
    int i = blockIdx.x * 256 + threadIdx.x;
    if (i < N_NODES) {
        inv_s[i] = 1.0f / sqrtf(fmaxf((float)cnt_s[i], 1.f));
        inv_r[i] = 1.0f / sqrtf(fmaxf((float)cnt_r[i], 1.f));
    }
}

__global__ __launch_bounds__(1024) void k_scan(const int* __restrict__ cnt,
                                               int* __restrict__ row_ptr) {
    __shared__ int part[1024];
    int t = threadIdx.x;
    int base = t * 64;
    int s = 0;
    #pragma unroll 8
    for (int i = 0; i < 64; ++i) s += cnt[base + i];
    part[t] = s;
    __syncthreads();
    for (int off = 1; off < 1024; off <<= 1) {
        int other = (t >= off) ? part[t - off] : 0;
        __syncthreads();
        part[t] += other;
        __syncthreads();
    }
    int run = part[t] - s;
    for (int i = 0; i < 64; ++i) {
        row_ptr[base + i] = run;
        run += cnt[base + i];
    }
    if (t == 1023) row_ptr[N_NODES] = run;
}

__global__ void k_fill(const int* __restrict__ senders, const int* __restrict__ receivers,
                       const int* __restrict__ row_ptr, int* __restrict__ cursor,
                       int* __restrict__ csr_send) {
    int e = blockIdx.x * 256 + threadIdx.x;
    if (e < E_EDGES) {
        int r = receivers[e];
        int pos = atomicAdd(&cursor[r], 1);
        csr_send[row_ptr[r] + pos] = senders[e];
    }
}

// ---------------- fp16 split helpers ----------------
// hi = f16(x); lo = f16(x - hi); n4 = n/4
__global__ void k_split(const float* __restrict__ src, _Float16* __restrict__ hi,
                        _Float16* __restrict__ lo, int n4) {
    int i = blockIdx.x * 256 + threadIdx.x;
    if (i >= n4) return;
    float4 v = ((const float4*)src)[i];
    f16x4 h, l;
    h[0] = (_Float16)v.x; h[1] = (_Float16)v.y; h[2] = (_Float16)v.z; h[3] = (_Float16)v.w;
    l[0] = (_Float16)(v.x - (float)h[0]);
    l[1] = (_Float16)(v.y - (float)h[1]);
    l[2] = (_Float16)(v.z - (float)h[2]);
    l[3] = (_Float16)(v.w - (float)h[3]);
    ((f16x4*)hi)[i] = h;
    ((f16x4*)lo)[i] = l;
}

// W[512][256] -> WT_hi/lo [256][512]
__global__ void k_splitWT(const float* __restrict__ W, _Float16* __restrict__ hiT,
                          _Float16* __restrict__ loT) {
    int idx = blockIdx.x * 256 + threadIdx.x;   // 131072
    int n = idx & (H_DIM - 1);
    int k = idx >> 8;
    float x = W[(size_t)k * H_DIM + n];
    _Float16 h = (_Float16)x;
    hiT[(size_t)n * F_DIM + k] = h;
    loT[(size_t)n * F_DIM + k] = (_Float16)(x - (float)h);
}

// ---------------- MFMA GEMM: X = (A @ B^T + bias) * inv_s ----------------
// A split hi/lo [M][K]; BT split hi/lo [N][K]; 128x128 tile, 4 waves, 4x4 frags 16x16x32
#define MFMA3(accv, AH, AL, BH, BL) \
    accv = __builtin_amdgcn_mfma_f32_16x16x32_f16(AH, BH, accv, 0, 0, 0); \
    accv = __builtin_amdgcn_mfma_f32_16x16x32_f16(AH, BL, accv, 0, 0, 0); \
    accv = __builtin_amdgcn_mfma_f32_16x16x32_f16(AL, BH, accv, 0, 0, 0);

#define STAGE_TILE(K) \
    *(float4*)&Ah[sr][skh]     = *(const float4*)(gAh + k0); \
    *(float4*)&Ah[sr][skh + 8] = *(const float4*)(gAh + k0 + 8); \
    *(float4*)&Al[sr][skh]     = *(const float4*)(gAl + k0); \
    *(float4*)&Al[sr][skh + 8] = *(const float4*)(gAl + k0 + 8); \
    *(float4*)&Bh[sr][skh]     = *(const float4*)(gBh + k0); \
    *(float4*)&Bh[sr][skh + 8] = *(const float4*)(gBh + k0 + 8); \
    *(float4*)&Bl[sr][skh]     = *(const float4*)(gBl + k0); \
    *(float4*)&Bl[sr][skh + 8] = *(const float4*)(gBl + k0 + 8);

#define MFMA_CORE \
    f16x8 ah[4], al[4]; \
    _Pragma("unroll") \
    for (int mi = 0; mi < 4; ++mi) { \
        ah[mi] = *(f16x8*)&Ah[wm * 64 + mi * 16 + lrow][kg * 8]; \
        al[mi] = *(f16x8*)&Al[wm * 64 + mi * 16 + lrow][kg * 8]; \
    } \
    _Pragma("unroll") \
    for (int ni = 0; ni < 4; ++ni) { \
        f16x8 bh = *(f16x8*)&Bh[wn * 64 + ni * 16 + lrow][kg * 8]; \
        f16x8 bl = *(f16x8*)&Bl[wn * 64 + ni * 16 + lrow][kg * 8]; \
        _Pragma("unroll") \
        for (int mi = 0; mi < 4; ++mi) { MFMA3(acc[mi][ni], ah[mi], al[mi], bh, bl) } \
    }

__global__ __launch_bounds__(256) void k_gemm_mfma(
    const _Float16* __restrict__ Ahi, const _Float16* __restrict__ Alo,
    const _Float16* __restrict__ BThi, const _Float16* __restrict__ BTlo,
    const float* __restrict__ bias, const float* __restrict__ inv_s,
    float* __restrict__ X, int K) {
    __shared__ _Float16 Ah[128][40], Al[128][40], Bh[128][40], Bl[128][40];
    const int t = threadIdx.x;
    const int lane = t & 63;
    const int wm = (t >> 6) >> 1, wn = (t >> 6) & 1;
    const int lrow = lane & 15, kg = lane >> 4;
    const int m0 = blockIdx.x * 128, n0 = blockIdx.y * 128;
    const int sr = t >> 1, skh = (t & 1) << 4;
    const _Float16* gAh = Ahi + (size_t)(m0 + sr) * K + skh;
    const _Float16* gAl = Alo + (size_t)(m0 + sr) * K + skh;
    const _Float16* gBh = BThi + (size_t)(n0 + sr) * K + skh;
    const _Float16* gBl = BTlo + (size_t)(n0 + sr) * K + skh;
    f32x4_t acc[4][4] = {};
    for (int k0 = 0; k0 < K; k0 += 32) {
        __syncthreads();
        STAGE_TILE(K)
        __syncthreads();
        MFMA_CORE
    }
    #pragma unroll
    for (int ni = 0; ni < 4; ++ni) {
        int col = n0 + wn * 64 + ni * 16 + lrow;
        float bc = bias[col];
        #pragma unroll
        for (int mi = 0; mi < 4; ++mi) {
            #pragma unroll
            for (int j = 0; j < 4; ++j) {
                int row = m0 + wm * 64 + mi * 16 + kg * 4 + j;
                X[(size_t)row * H_DIM + col] = (acc[mi][ni][j] + bc) * inv_s[row];
            }
        }
    }
}

// ---------------- MFMA cluster: d2 = e2 + c2 - 2*emb@centers^T, min/argmin ----------------
__global__ __launch_bounds__(256) void k_cluster_mfma(
    const _Float16* __restrict__ Ehi, const _Float16* __restrict__ Elo,
    const _Float16* __restrict__ Chi, const _Float16* __restrict__ Clo,
    const float* __restrict__ e2, const float* __restrict__ c2,
    unsigned* __restrict__ node_min, unsigned long long* __restrict__ center_min) {
    __shared__ _Float16 Ah[128][40], Al[128][40], Bh[128][40], Bl[128][40];
    __shared__ unsigned s_nmin[128];
    __shared__ unsigned long long s_cmin[128];
    const int t = threadIdx.x;
    const int lane = t & 63;
    const int wm = (t >> 6) >> 1, wn = (t >> 6) & 1;
    const int lrow = lane & 15, kg = lane >> 4;
    const int m0 = blockIdx.x * 128, n0 = blockIdx.y * 128;
    const int sr = t >> 1, skh = (t & 1) << 4;
    const int K = H_DIM;
    const _Float16* gAh = Ehi + (size_t)(m0 + sr) * K + skh;
    const _Float16* gAl = Elo + (size_t)(m0 + sr) * K + skh;
    const _Float16* gBh = Chi + (size_t)(n0 + sr) * K + skh;
    const _Float16* gBl = Clo + (size_t)(n0 + sr) * K + skh;
    if (t < 128) { s_nmin[t] = 0x7F800000u; s_cmin[t] = ~0ull; }
    f32x4_t acc[4][4] = {};
    for (int k0 = 0; k0 < K; k0 += 32) {
        __syncthreads();
        STAGE_TILE(K)
        __syncthreads();
        MFMA_CORE
    }
    // epilogue: distances + reductions (D layout: row = kg*4+j, col = lrow within frag)
    float cv[4];
    #pragma unroll
    for (int ni = 0; ni < 4; ++ni) cv[ni] = c2[n0 + wn * 64 + ni * 16 + lrow];
    unsigned long long cb[4] = {~0ull, ~0ull, ~0ull, ~0ull};
    #pragma unroll
    for (int mi = 0; mi < 4; ++mi) {
        #pragma unroll
        for (int j = 0; j < 4; ++j) {
            int lr = wm * 64 + mi * 16 + kg * 4 + j;
            int row = m0 + lr;
            float ev = e2[row];
            float rmin = 3.402823466e+38f;
            #pragma unroll
            for (int ni = 0; ni < 4; ++ni) {
                float d2 = ev + cv[ni] - 2.f * acc[mi][ni][j];
                float d = sqrtf(fmaxf(d2, 1e-12f));
                rmin = fminf(rmin, d);
                unsigned long long pk = ((unsigned long long)__float_as_uint(d) << 32) | (unsigned)row;
                if (pk < cb[ni]) cb[ni] = pk;
            }
            atomicMin(&s_nmin[lr], __float_as_uint(rmin));
        }
    }
    #pragma unroll
    for (int ni = 0; ni < 4; ++ni)
        atomicMin(&s_cmin[wn * 64 + ni * 16 + lrow], cb[ni]);
    __syncthreads();
    if (t < 128) {
        atomicMin(&node_min[m0 + t], s_nmin[t]);
        atomicMin(&center_min[n0 + t], s_cmin[t]);
    }
}

// ---------------- f32 fallback GEMM kernels (R4, proven) ----------------
#define FMA_ROW(accv, s, bv) accv.x += (s)*(bv).x; accv.y += (s)*(bv).y; accv.z += (s)*(bv).z; accv.w += (s)*(bv).w;
#define MT(ih, jh, av, bv) \
    FMA_ROW(acc[ih][jh][0], (av).x, bv) \
    FMA_ROW(acc[ih][jh][1], (av).y, bv) \
    FMA_ROW(acc[ih][jh][2], (av).z, bv) \
    FMA_ROW(acc[ih][jh][3], (av).w, bv)

__global__ __launch_bounds__(256) void k_gemm128(
    const float* __restrict__ A, const float* __restrict__ W,
    const float* __restrict__ bias, const float* __restrict__ inv_s,
    float* __restrict__ X) {
    __shared__ float As[16][132];
    __shared__ float Bs[16][132];
    const int t = threadIdx.x;
    const int tm = t >> 4, tn = t & 15;
    const int m0 = blockIdx.x * 128;
    const int n0 = blockIdx.y * 128;
    const int sm = t >> 1;
    const int sk = (t & 1) << 3;
    const int bk = t >> 5;
    const int bn = (t & 31) << 2;
    float4 acc[2][2][4] = {};
    const float* Arow = A + (size_t)(m0 + sm) * F_DIM;
    for (int k0 = 0; k0 < F_DIM; k0 += 16) {
        float4 va = *(const float4*)&Arow[k0 + sk];
        float4 vb = *(const float4*)&Arow[k0 + sk + 4];
        As[sk + 0][sm] = va.x; As[sk + 1][sm] = va.y; As[sk + 2][sm] = va.z; As[sk + 3][sm] = va.w;
        As[sk + 4][sm] = vb.x; As[sk + 5][sm] = vb.y; As[sk + 6][sm] = vb.z; As[sk + 7][sm] = vb.w;
        *(float4*)&Bs[bk][bn]     = *(const float4*)&W[(size_t)(k0 + bk) * H_DIM + n0 + bn];
        *(float4*)&Bs[bk + 8][bn] = *(const float4*)&W[(size_t)(k0 + bk + 8) * H_DIM + n0 + bn];
        __syncthreads();
        #pragma unroll
        for (int k = 0; k < 16; ++k) {
            float4 a0 = *(float4*)&As[k][tm << 2];
            float4 a1 = *(float4*)&As[k][64 + (tm << 2)];
            float4 b0 = *(float4*)&Bs[k][tn << 2];
            float4 b1 = *(float4*)&Bs[k][64 + (tn << 2)];
            MT(0, 0, a0, b0) MT(0, 1, a0, b1) MT(1, 0, a1, b0) MT(1, 1, a1, b1)
        }
        __syncthreads();
    }
    float4 bv[2];
    bv[0] = *(const float4*)&bias[n0 + (tn << 2)];
    bv[1] = *(const float4*)&bias[n0 + 64 + (tn << 2)];
    #pragma unroll
    for (int ih = 0; ih < 2; ++ih)
        #pragma unroll
        for (int i = 0; i < 4; ++i) {
            int row = m0 + ih * 64 + (tm << 2) + i;
            float w = inv_s[row];
            #pragma unroll
            for (int jh = 0; jh < 2; ++jh) {
                float4 o;
                o.x = (acc[ih][jh][i].x + bv[jh].x) * w;
                o.y = (acc[ih][jh][i].y + bv[jh].y) * w;
                o.z = (acc[ih][jh][i].z + bv[jh].z) * w;
                o.w = (acc[ih][jh][i].w + bv[jh].w) * w;
                *(float4*)&X[(size_t)row * H_DIM + n0 + jh * 64 + (tn << 2)] = o;
            }
        }
}

#define DCOMP(ih, jh, i, comp, j) { \
    float d2_ = ev + c2v[jh].comp - 2.f * acc[ih][jh][i].comp; \
    float d_ = sqrtf(fmaxf(d2_, 1e-12f)); \
    rmin = fminf(rmin, d_); \
    unsigned long long pk_ = ((unsigned long long)__float_as_uint(d_) << 32) | (unsigned)row; \
    if (pk_ < cb[jh][j]) cb[jh][j] = pk_; }
#define DJH(ih, jh, i) \
    DCOMP(ih, jh, i, x, 0) DCOMP(ih, jh, i, y, 1) DCOMP(ih, jh, i, z, 2) DCOMP(ih, jh, i, w, 3)

__global__ __launch_bounds__(256) void k_cluster128(
    const float* __restrict__ emb, const float* __restrict__ centers,
    const float* __restrict__ e2, const float* __restrict__ c2,
    unsigned* __restrict__ node_min, unsigned long long* __restrict__ center_min) {
    __shared__ float As[16][132];
    __shared__ float Bs[16][132];
    __shared__ unsigned s_nmin[128];
    __shared__ unsigned long long s_cmin[128];
    const int t = threadIdx.x;
    const int tm = t >> 4, tn = t & 15;
    const int m0 = blockIdx.x * 128;
    const int n0 = blockIdx.y * 128;
    const int sm = t >> 1;
    const int sk = (t & 1) << 3;
    const int cn = t >> 2;
    const int ck = (t & 3) << 2;
    float4 acc[2][2][4] = {};
    const float* Arow = emb + (size_t)(m0 + sm) * H_DIM;
    const float* C0 = centers + (size_t)(n0 + cn) * H_DIM;
    const float* C1 = centers + (size_t)(n0 + cn + 64) * H_DIM;
    for (int k0 = 0; k0 < H_DIM; k0 += 16) {
        float4 va = *(const float4*)&Arow[k0 + sk];
        float4 vb = *(const float4*)&Arow[k0 + sk + 4];
        As[sk + 0][sm] = va.x; As[sk + 1][sm] = va.y; As[sk + 2][sm] = va.z; As[sk + 3][sm] = va.w;
        As[sk + 4][sm] = vb.x; As[sk + 5][sm] = vb.y; As[sk + 6][sm] = vb.z; As[sk + 7][sm] = vb.w;
        float4 v0 = *(const float4*)&C0[k0 + ck];
        Bs[ck + 0][cn] = v0.x; Bs[ck + 1][cn] = v0.y; Bs[ck + 2][cn] = v0.z; Bs[ck + 3][cn] = v0.w;
        float4 v1 = *(const float4*)&C1[k0 + ck];
        Bs[ck + 0][cn + 64] = v1.x; Bs[ck + 1][cn + 64] = v1.y; Bs[ck + 2][cn + 64] = v1.z; Bs[ck + 3][cn + 64] = v1.w;
        __syncthreads();
        #pragma unroll
        for (int k = 0; k < 16; ++k) {
            float4 a0 = *(float4*)&As[k][tm << 2];
            float4 a1 = *(float4*)&As[k][64 + (tm << 2)];
            float4 b0 = *(float4*)&Bs[k][tn << 2];
            float4 b1 = *(float4*)&Bs[k][64 + (tn << 2)];
            MT(0, 0, a0, b0) MT(0, 1, a0, b1) MT(1, 0, a1, b0) MT(1, 1, a1, b1)
        }
        __syncthreads();
    }
    if (t < 128) { s_nmin[t] = 0x7F800000u; s_cmin[t] = ~0ull; }
    __syncthreads();
    float4 c2v[2];
    c2v[0] = *(const float4*)&c2[n0 + (tn << 2)];
    c2v[1] = *(const float4*)&c2[n0 + 64 + (tn << 2)];
    unsigned long long cb[2][4] = {{~0ull, ~0ull, ~0ull, ~0ull}, {~0ull, ~0ull, ~0ull, ~0ull}};
    #pragma unroll
    for (int ih = 0; ih < 2; ++ih)
        #pragma unroll
        for (int i = 0; i < 4; ++i) {
            int row = m0 + ih * 64 + (tm << 2) + i;
            float ev = e2[row];
            float rmin = 3.402823466e+38f;
            DJH(ih, 0, i) DJH(ih, 1, i)
            atomicMin(&s_nmin[ih * 64 + (tm << 2) + i], __float_as_uint(rmin));
        }
    #pragma unroll
    for (int jh = 0; jh < 2; ++jh)
        #pragma unroll
        for (int j = 0; j < 4; ++j)
            atomicMin(&s_cmin[jh * 64 + (tn << 2) + j], cb[jh][j]);
    __syncthreads();
    if (t < 128) {
        atomicMin(&node_min[m0 + t], s_nmin[t]);
        atomicMin(&center_min[n0 + t], s_cmin[t]);
    }
}

// ---------------- aggregation & misc (unchanged, proven) ----------------
__global__ __launch_bounds__(256) void k_agg1(
    const float* __restrict__ X, const int* __restrict__ csr_send,
    const int* __restrict__ row_ptr, const float* __restrict__ inv_r,
    float* __restrict__ out_emb) {
    int node = blockIdx.x * 4 + (threadIdx.x >> 6);
    int lane = threadIdx.x & 63;
    int beg = row_ptr[node], end = row_ptr[node + 1];
    float4 acc = {0.f, 0.f, 0.f, 0.f};
    for (int b = beg; b < end; b += 64) {
        int n = min(64, end - b);
        int myS = (lane < n) ? csr_send[b + lane] : 0;
        for (int i = 0; i < n; ++i) {
            int s = __shfl(myS, i);
            float4 x = *(const float4*)&X[(size_t)s * H_DIM + (lane << 2)];
            acc.x += x.x; acc.y += x.y; acc.z += x.z; acc.w += x.w;
        }
    }
    float ir = inv_r[node];
    float4 o;
    o.x = selu_f(acc.x * ir);
    o.y = selu_f(acc.y * ir);
    o.z = selu_f(acc.z * ir);
    o.w = selu_f(acc.w * ir);
    *(float4*)&out_emb[(size_t)node * H_DIM + (lane << 2)] = o;
}

__global__ __launch_bounds__(256) void k_agg2(
    const float* __restrict__ X, const int* __restrict__ csr_send,
    const int* __restrict__ row_ptr, const float* __restrict__ inv_r,
    const float* __restrict__ v, float* __restrict__ out) {
    int node = blockIdx.x * 4 + (threadIdx.x >> 6);
    int lane = threadIdx.x & 63;
    int beg = row_ptr[node], end = row_ptr[node + 1];
    float4 acc = {0.f, 0.f, 0.f, 0.f};
    for (int b = beg; b < end; b += 64) {
        int n = min(64, end - b);
        int myS = (lane < n) ? csr_send[b + lane] : 0;
        for (int i = 0; i < n; ++i) {
            int s = __shfl(myS, i);
            float4 x = *(const float4*)&X[(size_t)s * H_DIM + (lane << 2)];
            acc.x += x.x; acc.y += x.y; acc.z += x.z; acc.w += x.w;
        }
    }
    float ir = inv_r[node];
    float4 vv = *(const float4*)&v[lane << 2];
    float d = selu_f(acc.x * ir) * vv.x + selu_f(acc.y * ir) * vv.y
            + selu_f(acc.z * ir) * vv.z + selu_f(acc.w * ir) * vv.w;
    #pragma unroll
    for (int off = 32; off; off >>= 1) d += __shfl_down(d, off);
    if (lane == 0) out[node] = d;
}

__global__ __launch_bounds__(256) void k_colsum(const float* __restrict__ nodes1,
                                                float* __restrict__ colsum) {
    int t = threadIdx.x;
    size_t r0 = (size_t)blockIdx.x * 64;
    float s = 0.f;
    for (int r = 0; r < 64; ++r) s += nodes1[(r0 + r) * H_DIM + t];
    atomicAdd(&colsum[t], s);
}

__global__ void k_summary_v(const float* __restrict__ colsum, const float* __restrict__ Wb,
                            float* __restrict__ v) {
    __shared__ float s_sum[H_DIM];
    int t = threadIdx.x;
    float m = colsum[t] * (1.f / (float)N_NODES);
    s_sum[t] = 1.f / (1.f + expf(-m));
    __syncthreads();
    float acc = 0.f;
    for (int j = 0; j < H_DIM; ++j) acc += Wb[t * H_DIM + j] * s_sum[j];
    v[t] = acc;
}

__global__ __launch_bounds__(256) void k_normrow(
    float* __restrict__ emb, const float* __restrict__ v,
    float* __restrict__ logits, float* __restrict__ e2) {
    int row = blockIdx.x * 4 + (threadIdx.x >> 6);
    int lane = threadIdx.x & 63;
    float4 a = *(float4*)&emb[(size_t)row * H_DIM + (lane << 2)];
    float4 vv = *(const float4*)&v[lane << 2];
    float d = a.x * vv.x + a.y * vv.y + a.z * vv.z + a.w * vv.w;
    float ss = a.x * a.x + a.y * a.y + a.z * a.z + a.w * a.w;
    #pragma unroll
    for (int off = 32; off; off >>= 1) {
        d += __shfl_xor(d, off);
        ss += __shfl_xor(ss, off);
    }
    if (lane == 0) logits[row] = d;
    float inv = 1.f / sqrtf(ss);
    a.x *= inv; a.y *= inv; a.z *= inv; a.w *= inv;
    *(float4*)&emb[(size_t)row * H_DIM + (lane << 2)] = a;
    float s2 = a.x * a.x + a.y * a.y + a.z * a.z + a.w * a.w;
    #pragma unroll
    for (int off = 32; off; off >>= 1) s2 += __shfl_xor(s2, off);
    if (lane == 0) e2[row] = s2;
}

__global__ __launch_bounds__(256) void k_c2(const float* __restrict__ centers,
                                            float* __restrict__ c2) {
    int row = blockIdx.x * 4 + (threadIdx.x >> 6);
    int lane = threadIdx.x & 63;
    float4 a = *(const float4*)&centers[(size_t)row * H_DIM + (lane << 2)];
    float ss = a.x * a.x + a.y * a.y + a.z * a.z + a.w * a.w;
    #pragma unroll
    for (int off = 32; off; off >>= 1) ss += __shfl_xor(ss, off);
    if (lane == 0) c2[row] = ss;
}

__global__ __launch_bounds__(256) void k_loss(const unsigned* __restrict__ node_min,
                                              double* __restrict__ acc) {
    int i = blockIdx.x * 256 + threadIdx.x;
    float s = __uint_as_float(node_min[i]);
    #pragma unroll
    for (int off = 32; off; off >>= 1) s += __shfl_down(s, off);
    __shared__ float ws[4];
    int lane = threadIdx.x & 63, w = threadIdx.x >> 6;
    if (lane == 0) ws[w] = s;
    __syncthreads();
    if (threadIdx.x == 0) {
        float tot = ws[0] + ws[1] + ws[2] + ws[3];
        atomicAdd(acc, (double)tot);
    }
}

__global__ void k_finalize(const unsigned long long* __restrict__ center_min,
                           const double* __restrict__ loss_acc,
                           float* __restrict__ rep_out, float* __restrict__ loss_out) {
    int t = blockIdx.x * 256 + threadIdx.x;
    if (t < R_REPS) rep_out[t] = (float)(unsigned)(center_min[t] & 0xFFFFFFFFull);
    if (t == 0) *loss_out = (float)(*loss_acc);
}

extern "C" void kernel_launch(void* const* d_in, const int* in_sizes, int n_in,
                              void* d_out, int out_size, void* d_ws, size_t ws_size,
                              hipStream_t stream) {
    const float* nodes   = (const float*)d_in[0];
    const float* c_nodes = (const float*)d_in[1];
    const int* senders   = (const int*)d_in[2];
    const int* receivers = (const int*)d_in[3];
    const float* W       = (const float*)d_in[4];
    const float* bias    = (const float*)d_in[5];
    const float* Wb      = (const float*)d_in[6];
    const float* centers = (const float*)d_in[7];

    float* out = (float*)d_out;
    float* out_emb    = out;
    float* out_cent   = out + (size_t)N_NODES * H_DIM;
    float* out_rep    = out_cent + (size_t)R_REPS * H_DIM;
    float* out_loss   = out_rep + R_REPS;
    float* out_logits = out_loss + 1;

    char* wp = (char*)d_ws;
    unsigned long long* center_min = (unsigned long long*)wp; wp += (size_t)R_REPS * 8;
    double* loss_acc = (double*)wp;             wp += 8;
    float* X = (float*)wp;                      wp += (size_t)N_NODES * H_DIM * 4;
    int* csr_send = (int*)wp;                   wp += (size_t)E_EDGES * 4;
    int* row_ptr = (int*)wp;                    wp += (size_t)(N_NODES + 2) * 4;
    int* cursor = (int*)wp;                     wp += (size_t)N_NODES * 4;
    int* cnt_s = (int*)wp;                      wp += (size_t)N_NODES * 4;
    int* cnt_r = (int*)wp;                      wp += (size_t)N_NODES * 4;
    float* inv_s = (float*)wp;                  wp += (size_t)N_NODES * 4;
    float* inv_r = (float*)wp;                  wp += (size_t)N_NODES * 4;
    float* colsum = (float*)wp;                 wp += (size_t)H_DIM * 4;
    float* v = (float*)wp;                      wp += (size_t)H_DIM * 4;
    float* e2 = (float*)wp;                     wp += (size_t)N_NODES * 4;
    float* c2 = (float*)wp;                     wp += (size_t)R_REPS * 4;
    unsigned* node_min = (unsigned*)wp;         wp += (size_t)N_NODES * 4;
    // fp16 split buffers (mfma path only)
    _Float16* Ahi = (_Float16*)wp;              wp += (size_t)N_NODES * F_DIM * 2;
    _Float16* Alo = (_Float16*)wp;              wp += (size_t)N_NODES * F_DIM * 2;
    _Float16* WhiT = (_Float16*)wp;             wp += (size_t)H_DIM * F_DIM * 2;
    _Float16* WloT = (_Float16*)wp;             wp += (size_t)H_DIM * F_DIM * 2;
    _Float16* Chi = (_Float16*)wp;              wp += (size_t)R_REPS * H_DIM * 2;
    _Float16* Clo = (_Float16*)wp;              wp += (size_t)R_REPS * H_DIM * 2;
    const bool use_mfma = ((size_t)(wp - (char*)d_ws)) <= ws_size;

    k_init<<<N_NODES / 256, 256, 0, stream>>>(cnt_s, cnt_r, cursor, colsum, node_min, center_min, loss_acc);
    k_degree<<<E_EDGES / 256, 256, 0, stream>>>(senders, receivers, cnt_s, cnt_r);
    k_invsqrt<<<N_NODES / 256, 256, 0, stream>>>(cnt_s, cnt_r, inv_s, inv_r);
    k_scan<<<1, 1024, 0, stream>>>(cnt_r, row_ptr);
    k_fill<<<E_EDGES / 256, 256, 0, stream>>>(senders, receivers, row_ptr, cursor, csr_send);

    const int nA4 = N_NODES * F_DIM / 4;     // 8388608
    const int nE4 = N_NODES * H_DIM / 4;     // 4194304
    const int nC4 = R_REPS * H_DIM / 4;      // 32768

    if (use_mfma) {
        // GCN1 GEMM
        k_split<<<nA4 / 256, 256, 0, stream>>>(nodes, Ahi, Alo, nA4);
        k_splitWT<<<(F_DIM * H_DIM) / 256, 256, 0, stream>>>(W, WhiT, WloT);
        dim3 gg(N_NODES / 128, H_DIM / 128);
        k_gemm_mfma<<<gg, 256, 0, stream>>>(Ahi, Alo, WhiT, WloT, bias, inv_s, X, F_DIM);
    } else {
        dim3 gg(N_NODES / 128, H_DIM / 128);
        k_gemm128<<<gg, 256, 0, stream>>>(nodes, W, bias, inv_s, X);
    }
    k_agg1<<<N_NODES / 4, 256, 0, stream>>>(X, csr_send, row_ptr, inv_r, out_emb);

    k_colsum<<<N_NODES / 64, 256, 0, stream>>>(out_emb, colsum);
    k_summary_v<<<1, 256, 0, stream>>>(colsum, Wb, v);
    k_normrow<<<N_NODES / 4, 256, 0, stream>>>(out_emb, v, out_logits, e2);
    k_c2<<<R_REPS / 4, 256, 0, stream>>>(centers, c2);

    if (use_mfma) {
        k_split<<<nE4 / 256, 256, 0, stream>>>(out_emb, Ahi, Alo, nE4);
        k_split<<<nC4 / 256, 256, 0, stream>>>(centers, Chi, Clo, nC4);
        dim3 gc(N_NODES / 128, R_REPS / 128);
        k_cluster_mfma<<<gc, 256, 0, stream>>>(Ahi, Alo, Chi, Clo, e2, c2, node_min, center_min);
    } else {
        dim3 gc(N_NODES / 128, R_REPS / 128);
        k_cluster128<<<gc, 256, 0, stream>>>(out_emb, centers, e2, c2, node_min, center_min);
    }
    k_loss<<<N_NODES / 256, 256, 0, stream>>>(node_min, loss_acc);
    k_finalize<<<2, 256, 0, stream>>>(center_min, loss_acc, out_rep, out_loss);
    hipMemcpyAsync(out_cent, centers, (size_t)R_REPS * H_DIM * 4, hipMemcpyDeviceToDevice, stream);

    // GCN2
    if (use_mfma) {
        k_split<<<nA4 / 256, 256, 0, stream>>>(c_nodes, Ahi, Alo, nA4);
        dim3 gg(N_NODES / 128, H_DIM / 128);
        k_gemm_mfma<<<gg, 256, 0, stream>>>(Ahi, Alo, WhiT, WloT, bias, inv_s, X, F_DIM);
    } else {
        dim3 gg(N_NODES / 128, H_DIM / 128);
        k_gemm128<<<gg, 256, 0, stream>>>(c_nodes, W, bias, inv_s, X);
    }
    k_agg2<<<N_NODES / 4, 256, 0, stream>>>(X, csr_send, row_ptr, inv_r, v, out_logits + N_NODES);
}

// Round 9
// 903.075 us; speedup vs baseline: 1.4945x; 1.1077x over previous
//
#include <hip/hip_runtime.h>
#include <math.h>

#define N_NODES 65536
#define F_DIM 512
#define H_DIM 256
#define E_EDGES 1048576
#define R_REPS 512

typedef _Float16 f16x8 __attribute__((ext_vector_type(8)));
typedef float f32x4_t __attribute__((ext_vector_type(4)));

__device__ __forceinline__ float selu_f(float x) {
    const float SC = 1.0507009873554804934f;
    const float AL = 1.6732632423543772848f;
    return x > 0.f ? SC * x : SC * AL * expm1f(x);
}

// split 8 consecutive f32 -> hi/lo f16x8 (in-register, same rounding as old k_split)
__device__ __forceinline__ void split8(const float* __restrict__ g, f16x8* hi, f16x8* lo) {
    float4 v0 = *(const float4*)g;
    float4 v1 = *(const float4*)(g + 4);
    f16x8 h, l;
    h[0] = (_Float16)v0.x; h[1] = (_Float16)v0.y; h[2] = (_Float16)v0.z; h[3] = (_Float16)v0.w;
    h[4] = (_Float16)v1.x; h[5] = (_Float16)v1.y; h[6] = (_Float16)v1.z; h[7] = (_Float16)v1.w;
    l[0] = (_Float16)(v0.x - (float)h[0]); l[1] = (_Float16)(v0.y - (float)h[1]);
    l[2] = (_Float16)(v0.z - (float)h[2]); l[3] = (_Float16)(v0.w - (float)h[3]);
    l[4] = (_Float16)(v1.x - (float)h[4]); l[5] = (_Float16)(v1.y - (float)h[5]);
    l[6] = (_Float16)(v1.z - (float)h[6]); l[7] = (_Float16)(v1.w - (float)h[7]);
    *hi = h; *lo = l;
}

__global__ void k_init(int* cnt_s, int* cnt_r, float* colsum,
                       unsigned* node_min, unsigned long long* center_min,
                       double* loss_acc) {
    int i = blockIdx.x * 256 + threadIdx.x;
    if (i < N_NODES) { cnt_s[i] = 0; cnt_r[i] = 0; node_min[i] = 0x7F800000u; }
    if (i < H_DIM) colsum[i] = 0.f;
    if (i < R_REPS) center_min[i] = ~0ull;
    if (i == 0) *loss_acc = 0.0;
}

__global__ void k_degree(const int* __restrict__ senders, const int* __restrict__ receivers,
                         int* __restrict__ cnt_s, int* __restrict__ cnt_r) {
    int e = blockIdx.x * 256 + threadIdx.x;
    if (e < E_EDGES) {
        atomicAdd(&cnt_s[senders[e]], 1);
        atomicAdd(&cnt_r[receivers[e]], 1);
    }
}

__global__ void k_invsqrt(const int* __restrict__ cnt_s, const int* __restrict__ cnt_r,
                          float* __restrict__ inv_s, float* __restrict__ inv_r) {
    int i = blockIdx.x * 256 + threadIdx.x;
    if (i < N_NODES) {
        inv_s[i] = 1.0f / sqrtf(fmaxf((float)cnt_s[i], 1.f));
        inv_r[i] = 1.0f / sqrtf(fmaxf((float)cnt_r[i], 1.f));
    }
}

// scan cnt_r -> row_ptr; also prefill cursor = row_ptr (k_fill atomics on it directly)
__global__ __launch_bounds__(1024) void k_scan(const int* __restrict__ cnt,
                                               int* __restrict__ row_ptr,
                                               int* __restrict__ cursor) {
    __shared__ int part[1024];
    int t = threadIdx.x;
    int base = t * 64;
    int s = 0;
    #pragma unroll 8
    for (int i = 0; i < 64; ++i) s += cnt[base + i];
    part[t] = s;
    __syncthreads();
    for (int off = 1; off < 1024; off <<= 1) {
        int other = (t >= off) ? part[t - off] : 0;
        __syncthreads();
        part[t] += other;
        __syncthreads();
    }
    int run = part[t] - s;
    for (int i = 0; i < 64; ++i) {
        row_ptr[base + i] = run;
        cursor[base + i] = run;
        run += cnt[base + i];
    }
    if (t == 1023) row_ptr[N_NODES] = run;
}

__global__ void k_fill(const int* __restrict__ senders, const int* __restrict__ receivers,
                       int* __restrict__ cursor, int* __restrict__ csr_send) {
    int e = blockIdx.x * 256 + threadIdx.x;
    if (e < E_EDGES) {
        int pos = atomicAdd(&cursor[receivers[e]], 1);
        csr_send[pos] = senders[e];
    }
}

// W[512][256] -> WT_hi/lo [256][512] (tiny, stays a separate pass)
__global__ void k_splitWT(const float* __restrict__ W, _Float16* __restrict__ hiT,
                          _Float16* __restrict__ loT) {
    int idx = blockIdx.x * 256 + threadIdx.x;
    int n = idx & (H_DIM - 1);
    int k = idx >> 8;
    float x = W[(size_t)k * H_DIM + n];
    _Float16 h = (_Float16)x;
    hiT[(size_t)n * F_DIM + k] = h;
    loT[(size_t)n * F_DIM + k] = (_Float16)(x - (float)h);
}

#define MFMA3(accv, AH, AL, BH, BL) \
    accv = __builtin_amdgcn_mfma_f32_16x16x32_f16(AH, BH, accv, 0, 0, 0); \
    accv = __builtin_amdgcn_mfma_f32_16x16x32_f16(AH, BL, accv, 0, 0, 0); \
    accv = __builtin_amdgcn_mfma_f32_16x16x32_f16(AL, BH, accv, 0, 0, 0);

#define MFMA_CORE \
    f16x8 ah[4], al[4]; \
    _Pragma("unroll") \
    for (int mi = 0; mi < 4; ++mi) { \
        ah[mi] = *(f16x8*)&Ah[wm * 64 + mi * 16 + lrow][kg * 8]; \
        al[mi] = *(f16x8*)&Al[wm * 64 + mi * 16 + lrow][kg * 8]; \
    } \
    _Pragma("unroll") \
    for (int ni = 0; ni < 4; ++ni) { \
        f16x8 bh = *(f16x8*)&Bh[wn * 64 + ni * 16 + lrow][kg * 8]; \
        f16x8 bl = *(f16x8*)&Bl[wn * 64 + ni * 16 + lrow][kg * 8]; \
        _Pragma("unroll") \
        for (int mi = 0; mi < 4; ++mi) { MFMA3(acc[mi][ni], ah[mi], al[mi], bh, bl) } \
    }

// stage A-side from f32 with in-register hi/lo split
#define STAGE_A_F32(gA) { \
    f16x8 h0, l0, h1, l1; \
    split8((gA) + k0, &h0, &l0); \
    split8((gA) + k0 + 8, &h1, &l1); \
    *(f16x8*)&Ah[sr][skh] = h0; *(f16x8*)&Ah[sr][skh + 8] = h1; \
    *(f16x8*)&Al[sr][skh] = l0; *(f16x8*)&Al[sr][skh + 8] = l1; }

#define STAGE_B_F32(gB) { \
    f16x8 h0, l0, h1, l1; \
    split8((gB) + k0, &h0, &l0); \
    split8((gB) + k0 + 8, &h1, &l1); \
    *(f16x8*)&Bh[sr][skh] = h0; *(f16x8*)&Bh[sr][skh + 8] = h1; \
    *(f16x8*)&Bl[sr][skh] = l0; *(f16x8*)&Bl[sr][skh + 8] = l1; }

// X = (A @ WT^T + bias) * inv_s; A f32 (fused split), WT pre-split f16
__global__ __launch_bounds__(256) void k_gemm_mfma(
    const float* __restrict__ A,
    const _Float16* __restrict__ BThi, const _Float16* __restrict__ BTlo,
    const float* __restrict__ bias, const float* __restrict__ inv_s,
    float* __restrict__ X, int K) {
    __shared__ _Float16 Ah[128][40], Al[128][40], Bh[128][40], Bl[128][40];
    const int t = threadIdx.x;
    const int lane = t & 63;
    const int wm = (t >> 6) >> 1, wn = (t >> 6) & 1;
    const int lrow = lane & 15, kg = lane >> 4;
    const int m0 = blockIdx.x * 128, n0 = blockIdx.y * 128;
    const int sr = t >> 1, skh = (t & 1) << 4;
    const float* gA = A + (size_t)(m0 + sr) * K + skh;
    const _Float16* gBh = BThi + (size_t)(n0 + sr) * K + skh;
    const _Float16* gBl = BTlo + (size_t)(n0 + sr) * K + skh;
    f32x4_t acc[4][4] = {};
    for (int k0 = 0; k0 < K; k0 += 32) {
        __syncthreads();
        STAGE_A_F32(gA)
        *(float4*)&Bh[sr][skh]     = *(const float4*)(gBh + k0);
        *(float4*)&Bh[sr][skh + 8] = *(const float4*)(gBh + k0 + 8);
        *(float4*)&Bl[sr][skh]     = *(const float4*)(gBl + k0);
        *(float4*)&Bl[sr][skh + 8] = *(const float4*)(gBl + k0 + 8);
        __syncthreads();
        MFMA_CORE
    }
    #pragma unroll
    for (int ni = 0; ni < 4; ++ni) {
        int col = n0 + wn * 64 + ni * 16 + lrow;
        float bc = bias[col];
        #pragma unroll
        for (int mi = 0; mi < 4; ++mi) {
            #pragma unroll
            for (int j = 0; j < 4; ++j) {
                int row = m0 + wm * 64 + mi * 16 + kg * 4 + j;
                X[(size_t)row * H_DIM + col] = (acc[mi][ni][j] + bc) * inv_s[row];
            }
        }
    }
}

// cluster: both sides f32 with fused split; min/argmin epilogue on MFMA layout
__global__ __launch_bounds__(256) void k_cluster_mfma(
    const float* __restrict__ emb, const float* __restrict__ centers,
    const float* __restrict__ e2, const float* __restrict__ c2,
    unsigned* __restrict__ node_min, unsigned long long* __restrict__ center_min) {
    __shared__ _Float16 Ah[128][40], Al[128][40], Bh[128][40], Bl[128][40];
    __shared__ unsigned s_nmin[128];
    __shared__ unsigned long long s_cmin[128];
    const int t = threadIdx.x;
    const int lane = t & 63;
    const int wm = (t >> 6) >> 1, wn = (t >> 6) & 1;
    const int lrow = lane & 15, kg = lane >> 4;
    const int m0 = blockIdx.x * 128, n0 = blockIdx.y * 128;
    const int sr = t >> 1, skh = (t & 1) << 4;
    const int K = H_DIM;
    const float* gA = emb + (size_t)(m0 + sr) * K + skh;
    const float* gB = centers + (size_t)(n0 + sr) * K + skh;
    if (t < 128) { s_nmin[t] = 0x7F800000u; s_cmin[t] = ~0ull; }
    f32x4_t acc[4][4] = {};
    for (int k0 = 0; k0 < K; k0 += 32) {
        __syncthreads();
        STAGE_A_F32(gA)
        STAGE_B_F32(gB)
        __syncthreads();
        MFMA_CORE
    }
    float cv[4];
    #pragma unroll
    for (int ni = 0; ni < 4; ++ni) cv[ni] = c2[n0 + wn * 64 + ni * 16 + lrow];
    unsigned long long cb[4] = {~0ull, ~0ull, ~0ull, ~0ull};
    #pragma unroll
    for (int mi = 0; mi < 4; ++mi) {
        #pragma unroll
        for (int j = 0; j < 4; ++j) {
            int lr = wm * 64 + mi * 16 + kg * 4 + j;
            int row = m0 + lr;
            float ev = e2[row];
            float rmin = 3.402823466e+38f;
            #pragma unroll
            for (int ni = 0; ni < 4; ++ni) {
                float d2 = ev + cv[ni] - 2.f * acc[mi][ni][j];
                float d = sqrtf(fmaxf(d2, 1e-12f));
                rmin = fminf(rmin, d);
                unsigned long long pk = ((unsigned long long)__float_as_uint(d) << 32) | (unsigned)row;
                if (pk < cb[ni]) cb[ni] = pk;
            }
            atomicMin(&s_nmin[lr], __float_as_uint(rmin));
        }
    }
    #pragma unroll
    for (int ni = 0; ni < 4; ++ni)
        atomicMin(&s_cmin[wn * 64 + ni * 16 + lrow], cb[ni]);
    __syncthreads();
    if (t < 128) {
        atomicMin(&node_min[m0 + t], s_nmin[t]);
        atomicMin(&center_min[n0 + t], s_cmin[t]);
    }
}

// ---------------- aggregation & misc (unchanged, proven) ----------------
__global__ __launch_bounds__(256) void k_agg1(
    const float* __restrict__ X, const int* __restrict__ csr_send,
    const int* __restrict__ row_ptr, const float* __restrict__ inv_r,
    float* __restrict__ out_emb) {
    int node = blockIdx.x * 4 + (threadIdx.x >> 6);
    int lane = threadIdx.x & 63;
    int beg = row_ptr[node], end = row_ptr[node + 1];
    float4 acc = {0.f, 0.f, 0.f, 0.f};
    for (int b = beg; b < end; b += 64) {
        int n = min(64, end - b);
        int myS = (lane < n) ? csr_send[b + lane] : 0;
        for (int i = 0; i < n; ++i) {
            int s = __shfl(myS, i);
            float4 x = *(const float4*)&X[(size_t)s * H_DIM + (lane << 2)];
            acc.x += x.x; acc.y += x.y; acc.z += x.z; acc.w += x.w;
        }
    }
    float ir = inv_r[node];
    float4 o;
    o.x = selu_f(acc.x * ir);
    o.y = selu_f(acc.y * ir);
    o.z = selu_f(acc.z * ir);
    o.w = selu_f(acc.w * ir);
    *(float4*)&out_emb[(size_t)node * H_DIM + (lane << 2)] = o;
}

__global__ __launch_bounds__(256) void k_agg2(
    const float* __restrict__ X, const int* __restrict__ csr_send,
    const int* __restrict__ row_ptr, const float* __restrict__ inv_r,
    const float* __restrict__ v, float* __restrict__ out) {
    int node = blockIdx.x * 4 + (threadIdx.x >> 6);
    int lane = threadIdx.x & 63;
    int beg = row_ptr[node], end = row_ptr[node + 1];
    float4 acc = {0.f, 0.f, 0.f, 0.f};
    for (int b = beg; b < end; b += 64) {
        int n = min(64, end - b);
        int myS = (lane < n) ? csr_send[b + lane] : 0;
        for (int i = 0; i < n; ++i) {
            int s = __shfl(myS, i);
            float4 x = *(const float4*)&X[(size_t)s * H_DIM + (lane << 2)];
            acc.x += x.x; acc.y += x.y; acc.z += x.z; acc.w += x.w;
        }
    }
    float ir = inv_r[node];
    float4 vv = *(const float4*)&v[lane << 2];
    float d = selu_f(acc.x * ir) * vv.x + selu_f(acc.y * ir) * vv.y
            + selu_f(acc.z * ir) * vv.z + selu_f(acc.w * ir) * vv.w;
    #pragma unroll
    for (int off = 32; off; off >>= 1) d += __shfl_down(d, off);
    if (lane == 0) out[node] = d;
}

__global__ __launch_bounds__(256) void k_colsum(const float* __restrict__ nodes1,
                                                float* __restrict__ colsum) {
    int t = threadIdx.x;
    size_t r0 = (size_t)blockIdx.x * 64;
    float s = 0.f;
    for (int r = 0; r < 64; ++r) s += nodes1[(r0 + r) * H_DIM + t];
    atomicAdd(&colsum[t], s);
}

__global__ void k_summary_v(const float* __restrict__ colsum, const float* __restrict__ Wb,
                            float* __restrict__ v) {
    __shared__ float s_sum[H_DIM];
    int t = threadIdx.x;
    float m = colsum[t] * (1.f / (float)N_NODES);
    s_sum[t] = 1.f / (1.f + expf(-m));
    __syncthreads();
    float acc = 0.f;
    for (int j = 0; j < H_DIM; ++j) acc += Wb[t * H_DIM + j] * s_sum[j];
    v[t] = acc;
}

__global__ __launch_bounds__(256) void k_normrow(
    float* __restrict__ emb, const float* __restrict__ v,
    float* __restrict__ logits, float* __restrict__ e2) {
    int row = blockIdx.x * 4 + (threadIdx.x >> 6);
    int lane = threadIdx.x & 63;
    float4 a = *(float4*)&emb[(size_t)row * H_DIM + (lane << 2)];
    float4 vv = *(const float4*)&v[lane << 2];
    float d = a.x * vv.x + a.y * vv.y + a.z * vv.z + a.w * vv.w;
    float ss = a.x * a.x + a.y * a.y + a.z * a.z + a.w * a.w;
    #pragma unroll
    for (int off = 32; off; off >>= 1) {
        d += __shfl_xor(d, off);
        ss += __shfl_xor(ss, off);
    }
    if (lane == 0) logits[row] = d;
    float inv = 1.f / sqrtf(ss);
    a.x *= inv; a.y *= inv; a.z *= inv; a.w *= inv;
    *(float4*)&emb[(size_t)row * H_DIM + (lane << 2)] = a;
    float s2 = a.x * a.x + a.y * a.y + a.z * a.z + a.w * a.w;
    #pragma unroll
    for (int off = 32; off; off >>= 1) s2 += __shfl_xor(s2, off);
    if (lane == 0) e2[row] = s2;
}

__global__ __launch_bounds__(256) void k_c2(const float* __restrict__ centers,
                                            float* __restrict__ c2) {
    int row = blockIdx.x * 4 + (threadIdx.x >> 6);
    int lane = threadIdx.x & 63;
    float4 a = *(const float4*)&centers[(size_t)row * H_DIM + (lane << 2)];
    float ss = a.x * a.x + a.y * a.y + a.z * a.z + a.w * a.w;
    #pragma unroll
    for (int off = 32; off; off >>= 1) ss += __shfl_xor(ss, off);
    if (lane == 0) c2[row] = ss;
}

__global__ __launch_bounds__(256) void k_loss(const unsigned* __restrict__ node_min,
                                              double* __restrict__ acc) {
    int i = blockIdx.x * 256 + threadIdx.x;
    float s = __uint_as_float(node_min[i]);
    #pragma unroll
    for (int off = 32; off; off >>= 1) s += __shfl_down(s, off);
    __shared__ float ws[4];
    int lane = threadIdx.x & 63, w = threadIdx.x >> 6;
    if (lane == 0) ws[w] = s;
    __syncthreads();
    if (threadIdx.x == 0) {
        float tot = ws[0] + ws[1] + ws[2] + ws[3];
        atomicAdd(acc, (double)tot);
    }
}

__global__ void k_finalize(const unsigned long long* __restrict__ center_min,
                           const double* __restrict__ loss_acc,
                           float* __restrict__ rep_out, float* __restrict__ loss_out) {
    int t = blockIdx.x * 256 + threadIdx.x;
    if (t < R_REPS) rep_out[t] = (float)(unsigned)(center_min[t] & 0xFFFFFFFFull);
    if (t == 0) *loss_out = (float)(*loss_acc);
}

extern "C" void kernel_launch(void* const* d_in, const int* in_sizes, int n_in,
                              void* d_out, int out_size, void* d_ws, size_t ws_size,
                              hipStream_t stream) {
    const float* nodes   = (const float*)d_in[0];
    const float* c_nodes = (const float*)d_in[1];
    const int* senders   = (const int*)d_in[2];
    const int* receivers = (const int*)d_in[3];
    const float* W       = (const float*)d_in[4];
    const float* bias    = (const float*)d_in[5];
    const float* Wb      = (const float*)d_in[6];
    const float* centers = (const float*)d_in[7];

    float* out = (float*)d_out;
    float* out_emb    = out;
    float* out_cent   = out + (size_t)N_NODES * H_DIM;
    float* out_rep    = out_cent + (size_t)R_REPS * H_DIM;
    float* out_loss   = out_rep + R_REPS;
    float* out_logits = out_loss + 1;

    char* wp = (char*)d_ws;
    unsigned long long* center_min = (unsigned long long*)wp; wp += (size_t)R_REPS * 8;
    double* loss_acc = (double*)wp;             wp += 8;
    float* X = (float*)wp;                      wp += (size_t)N_NODES * H_DIM * 4;
    int* csr_send = (int*)wp;                   wp += (size_t)E_EDGES * 4;
    int* row_ptr = (int*)wp;                    wp += (size_t)(N_NODES + 2) * 4;
    int* cursor = (int*)wp;                     wp += (size_t)N_NODES * 4;
    int* cnt_s = (int*)wp;                      wp += (size_t)N_NODES * 4;
    int* cnt_r = (int*)wp;                      wp += (size_t)N_NODES * 4;
    float* inv_s = (float*)wp;                  wp += (size_t)N_NODES * 4;
    float* inv_r = (float*)wp;                  wp += (size_t)N_NODES * 4;
    float* colsum = (float*)wp;                 wp += (size_t)H_DIM * 4;
    float* v = (float*)wp;                      wp += (size_t)H_DIM * 4;
    float* e2 = (float*)wp;                     wp += (size_t)N_NODES * 4;
    float* c2 = (float*)wp;                     wp += (size_t)R_REPS * 4;
    unsigned* node_min = (unsigned*)wp;         wp += (size_t)N_NODES * 4;
    _Float16* WhiT = (_Float16*)wp;             wp += (size_t)H_DIM * F_DIM * 2;
    _Float16* WloT = (_Float16*)wp;             wp += (size_t)H_DIM * F_DIM * 2;

    k_init<<<N_NODES / 256, 256, 0, stream>>>(cnt_s, cnt_r, colsum, node_min, center_min, loss_acc);
    k_degree<<<E_EDGES / 256, 256, 0, stream>>>(senders, receivers, cnt_s, cnt_r);
    k_invsqrt<<<N_NODES / 256, 256, 0, stream>>>(cnt_s, cnt_r, inv_s, inv_r);
    k_scan<<<1, 1024, 0, stream>>>(cnt_r, row_ptr, cursor);
    k_fill<<<E_EDGES / 256, 256, 0, stream>>>(senders, receivers, cursor, csr_send);
    k_splitWT<<<(F_DIM * H_DIM) / 256, 256, 0, stream>>>(W, WhiT, WloT);

    dim3 gg(N_NODES / 128, H_DIM / 128);
    // GCN1
    k_gemm_mfma<<<gg, 256, 0, stream>>>(nodes, WhiT, WloT, bias, inv_s, X, F_DIM);
    k_agg1<<<N_NODES / 4, 256, 0, stream>>>(X, csr_send, row_ptr, inv_r, out_emb);

    k_colsum<<<N_NODES / 64, 256, 0, stream>>>(out_emb, colsum);
    k_summary_v<<<1, 256, 0, stream>>>(colsum, Wb, v);
    k_normrow<<<N_NODES / 4, 256, 0, stream>>>(out_emb, v, out_logits, e2);
    k_c2<<<R_REPS / 4, 256, 0, stream>>>(centers, c2);

    dim3 gc(N_NODES / 128, R_REPS / 128);
    k_cluster_mfma<<<gc, 256, 0, stream>>>(out_emb, centers, e2, c2, node_min, center_min);
    k_loss<<<N_NODES / 256, 256, 0, stream>>>(node_min, loss_acc);
    k_finalize<<<2, 256, 0, stream>>>(center_min, loss_acc, out_rep, out_loss);
    hipMemcpyAsync(out_cent, centers, (size_t)R_REPS * H_DIM * 4, hipMemcpyDeviceToDevice, stream);

    // GCN2 (reuse X; nodes2 never materialized)
    k_gemm_mfma<<<gg, 256, 0, stream>>>(c_nodes, WhiT, WloT, bias, inv_s, X, F_DIM);
    k_agg2<<<N_NODES / 4, 256, 0, stream>>>(X, csr_send, row_ptr, inv_r, v, out_logits + N_NODES);
}

// Round 11
// 902.151 us; speedup vs baseline: 1.4960x; 1.0010x over previous
//
#include <hip/hip_runtime.h>
#include <math.h>

#define N_NODES 65536
#define F_DIM 512
#define H_DIM 256
#define E_EDGES 1048576
#define R_REPS 512

typedef _Float16 f16x8 __attribute__((ext_vector_type(8)));
typedef float f32x4_t __attribute__((ext_vector_type(4)));

__device__ __forceinline__ float selu_f(float x) {
    const float SC = 1.0507009873554804934f;
    const float AL = 1.6732632423543772848f;
    return x > 0.f ? SC * x : SC * AL * expm1f(x);
}

// split 8 consecutive f32 -> hi/lo f16x8 (in-register)
__device__ __forceinline__ void split8(const float* __restrict__ g, f16x8* hi, f16x8* lo) {
    float4 v0 = *(const float4*)g;
    float4 v1 = *(const float4*)(g + 4);
    f16x8 h, l;
    h[0] = (_Float16)v0.x; h[1] = (_Float16)v0.y; h[2] = (_Float16)v0.z; h[3] = (_Float16)v0.w;
    h[4] = (_Float16)v1.x; h[5] = (_Float16)v1.y; h[6] = (_Float16)v1.z; h[7] = (_Float16)v1.w;
    l[0] = (_Float16)(v0.x - (float)h[0]); l[1] = (_Float16)(v0.y - (float)h[1]);
    l[2] = (_Float16)(v0.z - (float)h[2]); l[3] = (_Float16)(v0.w - (float)h[3]);
    l[4] = (_Float16)(v1.x - (float)h[4]); l[5] = (_Float16)(v1.y - (float)h[5]);
    l[6] = (_Float16)(v1.z - (float)h[6]); l[7] = (_Float16)(v1.w - (float)h[7]);
    *hi = h; *lo = l;
}

// 64-lane bitonic sort (ascending) of one int per lane — makes bucket order
// a pure function of bucket CONTENTS (defuses csr fill-order nondeterminism)
__device__ __forceinline__ int wave_sort64(int v, int lane) {
    #pragma unroll
    for (int k = 2; k <= 64; k <<= 1) {
        #pragma unroll
        for (int j = k >> 1; j > 0; j >>= 1) {
            int p = __shfl_xor(v, j);
            bool takeMin = (((lane & j) == 0) == ((lane & k) == 0));
            int mn = min(v, p), mx = max(v, p);
            v = takeMin ? mn : mx;
        }
    }
    return v;
}

__global__ void k_init(int* cnt_s, int* cnt_r, float* colsum,
                       unsigned* node_min, unsigned long long* center_min,
                       double* loss_acc) {
    int i = blockIdx.x * 256 + threadIdx.x;
    if (i < N_NODES) { cnt_s[i] = 0; cnt_r[i] = 0; node_min[i] = 0x7F800000u; }
    if (i < H_DIM) colsum[i] = 0.f;
    if (i < R_REPS) center_min[i] = ~0ull;
    if (i == 0) *loss_acc = 0.0;
}

__global__ void k_degree(const int* __restrict__ senders, const int* __restrict__ receivers,
                         int* __restrict__ cnt_s, int* __restrict__ cnt_r) {
    int e = blockIdx.x * 256 + threadIdx.x;
    if (e < E_EDGES) {
        atomicAdd(&cnt_s[senders[e]], 1);
        atomicAdd(&cnt_r[receivers[e]], 1);
    }
}

__global__ void k_invsqrt(const int* __restrict__ cnt_s, const int* __restrict__ cnt_r,
                          float* __restrict__ inv_s, float* __restrict__ inv_r) {
    int i = blockIdx.x * 256 + threadIdx.x;
    if (i < N_NODES) {
        inv_s[i] = 1.0f / sqrtf(fmaxf((float)cnt_s[i], 1.f));
        inv_r[i] = 1.0f / sqrtf(fmaxf((float)cnt_r[i], 1.f));
    }
}

__global__ __launch_bounds__(1024) void k_scan(const int* __restrict__ cnt,
                                               int* __restrict__ row_ptr,
                                               int* __restrict__ cursor) {
    __shared__ int part[1024];
    int t = threadIdx.x;
    int base = t * 64;
    int s = 0;
    #pragma unroll 8
    for (int i = 0; i < 64; ++i) s += cnt[base + i];
    part[t] = s;
    __syncthreads();
    for (int off = 1; off < 1024; off <<= 1) {
        int other = (t >= off) ? part[t - off] : 0;
        __syncthreads();
        part[t] += other;
        __syncthreads();
    }
    int run = part[t] - s;
    for (int i = 0; i < 64; ++i) {
        row_ptr[base + i] = run;
        cursor[base + i] = run;
        run += cnt[base + i];
    }
    if (t == 1023) row_ptr[N_NODES] = run;
}

__global__ void k_fill(const int* __restrict__ senders, const int* __restrict__ receivers,
                       int* __restrict__ cursor, int* __restrict__ csr_send) {
    int e = blockIdx.x * 256 + threadIdx.x;
    if (e < E_EDGES) {
        int pos = atomicAdd(&cursor[receivers[e]], 1);
        csr_send[pos] = senders[e];
    }
}

// W[512][256] -> WT_hi/lo [256][512]
__global__ void k_splitWT(const float* __restrict__ W, _Float16* __restrict__ hiT,
                          _Float16* __restrict__ loT) {
    int idx = blockIdx.x * 256 + threadIdx.x;
    int n = idx & (H_DIM - 1);
    int k = idx >> 8;
    float x = W[(size_t)k * H_DIM + n];
    _Float16 h = (_Float16)x;
    hiT[(size_t)n * F_DIM + k] = h;
    loT[(size_t)n * F_DIM + k] = (_Float16)(x - (float)h);
}

#define MFMA3(accv, AH, AL, BH, BL) \
    accv = __builtin_amdgcn_mfma_f32_16x16x32_f16(AH, BH, accv, 0, 0, 0); \
    accv = __builtin_amdgcn_mfma_f32_16x16x32_f16(AH, BL, accv, 0, 0, 0); \
    accv = __builtin_amdgcn_mfma_f32_16x16x32_f16(AL, BH, accv, 0, 0, 0);

#define MFMA_CORE \
    f16x8 ah[4], al[4]; \
    _Pragma("unroll") \
    for (int mi = 0; mi < 4; ++mi) { \
        ah[mi] = *(f16x8*)&Ah[wm * 64 + mi * 16 + lrow][kg * 8]; \
        al[mi] = *(f16x8*)&Al[wm * 64 + mi * 16 + lrow][kg * 8]; \
    } \
    _Pragma("unroll") \
    for (int ni = 0; ni < 4; ++ni) { \
        f16x8 bh = *(f16x8*)&Bh[wn * 64 + ni * 16 + lrow][kg * 8]; \
        f16x8 bl = *(f16x8*)&Bl[wn * 64 + ni * 16 + lrow][kg * 8]; \
        _Pragma("unroll") \
        for (int mi = 0; mi < 4; ++mi) { MFMA3(acc[mi][ni], ah[mi], al[mi], bh, bl) } \
    }

#define STAGE_A_F32(gA) { \
    f16x8 h0, l0, h1, l1; \
    split8((gA) + k0, &h0, &l0); \
    split8((gA) + k0 + 8, &h1, &l1); \
    *(f16x8*)&Ah[sr][skh] = h0; *(f16x8*)&Ah[sr][skh + 8] = h1; \
    *(f16x8*)&Al[sr][skh] = l0; *(f16x8*)&Al[sr][skh + 8] = l1; }

#define STAGE_B_F32(gB) { \
    f16x8 h0, l0, h1, l1; \
    split8((gB) + k0, &h0, &l0); \
    split8((gB) + k0 + 8, &h1, &l1); \
    *(f16x8*)&Bh[sr][skh] = h0; *(f16x8*)&Bh[sr][skh + 8] = h1; \
    *(f16x8*)&Bl[sr][skh] = l0; *(f16x8*)&Bl[sr][skh + 8] = l1; }

// X = (A @ WT^T + bias) * inv_s; A f32 (fused split), WT pre-split f16
__global__ __launch_bounds__(256) void k_gemm_mfma(
    const float* __restrict__ A,
    const _Float16* __restrict__ BThi, const _Float16* __restrict__ BTlo,
    const float* __restrict__ bias, const float* __restrict__ inv_s,
    float* __restrict__ X, int K) {
    __shared__ _Float16 Ah[128][40], Al[128][40], Bh[128][40], Bl[128][40];
    const int t = threadIdx.x;
    const int lane = t & 63;
    const int wm = (t >> 6) >> 1, wn = (t >> 6) & 1;
    const int lrow = lane & 15, kg = lane >> 4;
    const int m0 = blockIdx.x * 128, n0 = blockIdx.y * 128;
    const int sr = t >> 1, skh = (t & 1) << 4;
    const float* gA = A + (size_t)(m0 + sr) * K + skh;
    const _Float16* gBh = BThi + (size_t)(n0 + sr) * K + skh;
    const _Float16* gBl = BTlo + (size_t)(n0 + sr) * K + skh;
    f32x4_t acc[4][4] = {};
    for (int k0 = 0; k0 < K; k0 += 32) {
        __syncthreads();
        STAGE_A_F32(gA)
        *(float4*)&Bh[sr][skh]     = *(const float4*)(gBh + k0);
        *(float4*)&Bh[sr][skh + 8] = *(const float4*)(gBh + k0 + 8);
        *(float4*)&Bl[sr][skh]     = *(const float4*)(gBl + k0);
        *(float4*)&Bl[sr][skh + 8] = *(const float4*)(gBl + k0 + 8);
        __syncthreads();
        MFMA_CORE
    }
    #pragma unroll
    for (int ni = 0; ni < 4; ++ni) {
        int col = n0 + wn * 64 + ni * 16 + lrow;
        float bc = bias[col];
        #pragma unroll
        for (int mi = 0; mi < 4; ++mi) {
            #pragma unroll
            for (int j = 0; j < 4; ++j) {
                int row = m0 + wm * 64 + mi * 16 + kg * 4 + j;
                X[(size_t)row * H_DIM + col] = (acc[mi][ni][j] + bc) * inv_s[row];
            }
        }
    }
}

// cluster: both sides f32 with fused split; min/argmin epilogue on MFMA layout
__global__ __launch_bounds__(256) void k_cluster_mfma(
    const float* __restrict__ emb, const float* __restrict__ centers,
    const float* __restrict__ e2, const float* __restrict__ c2,
    unsigned* __restrict__ node_min, unsigned long long* __restrict__ center_min) {
    __shared__ _Float16 Ah[128][40], Al[128][40], Bh[128][40], Bl[128][40];
    __shared__ unsigned s_nmin[128];
    __shared__ unsigned long long s_cmin[128];
    const int t = threadIdx.x;
    const int lane = t & 63;
    const int wm = (t >> 6) >> 1, wn = (t >> 6) & 1;
    const int lrow = lane & 15, kg = lane >> 4;
    const int m0 = blockIdx.x * 128, n0 = blockIdx.y * 128;
    const int sr = t >> 1, skh = (t & 1) << 4;
    const int K = H_DIM;
    const float* gA = emb + (size_t)(m0 + sr) * K + skh;
    const float* gB = centers + (size_t)(n0 + sr) * K + skh;
    if (t < 128) { s_nmin[t] = 0x7F800000u; s_cmin[t] = ~0ull; }
    f32x4_t acc[4][4] = {};
    for (int k0 = 0; k0 < K; k0 += 32) {
        __syncthreads();
        STAGE_A_F32(gA)
        STAGE_B_F32(gB)
        __syncthreads();
        MFMA_CORE
    }
    float cv[4];
    #pragma unroll
    for (int ni = 0; ni < 4; ++ni) cv[ni] = c2[n0 + wn * 64 + ni * 16 + lrow];
    unsigned long long cb[4] = {~0ull, ~0ull, ~0ull, ~0ull};
    #pragma unroll
    for (int mi = 0; mi < 4; ++mi) {
        #pragma unroll
        for (int j = 0; j < 4; ++j) {
            int lr = wm * 64 + mi * 16 + kg * 4 + j;
            int row = m0 + lr;
            float ev = e2[row];
            float rmin = 3.402823466e+38f;
            #pragma unroll
            for (int ni = 0; ni < 4; ++ni) {
                float d2 = ev + cv[ni] - 2.f * acc[mi][ni][j];
                float d = sqrtf(fmaxf(d2, 1e-12f));
                rmin = fminf(rmin, d);
                unsigned long long pk = ((unsigned long long)__float_as_uint(d) << 32) | (unsigned)row;
                if (pk < cb[ni]) cb[ni] = pk;
            }
            atomicMin(&s_nmin[lr], __float_as_uint(rmin));
        }
    }
    #pragma unroll
    for (int ni = 0; ni < 4; ++ni)
        atomicMin(&s_cmin[wn * 64 + ni * 16 + lrow], cb[ni]);
    __syncthreads();
    if (t < 128) {
        atomicMin(&node_min[m0 + t], s_nmin[t]);
        atomicMin(&center_min[n0 + t], s_cmin[t]);
    }
}

// one wave per node; bucket chunk sorted by sender id -> bit-deterministic sum
__global__ __launch_bounds__(256) void k_agg1(
    const float* __restrict__ X, const int* __restrict__ csr_send,
    const int* __restrict__ row_ptr, const float* __restrict__ inv_r,
    float* __restrict__ out_emb) {
    int node = blockIdx.x * 4 + (threadIdx.x >> 6);
    int lane = threadIdx.x & 63;
    int beg = row_ptr[node], end = row_ptr[node + 1];
    float4 acc = {0.f, 0.f, 0.f, 0.f};
    for (int b = beg; b < end; b += 64) {
        int n = min(64, end - b);
        int myS = (lane < n) ? csr_send[b + lane] : 0x7FFFFFFF;
        myS = wave_sort64(myS, lane);
        for (int i = 0; i < n; ++i) {
            int s = __shfl(myS, i);
            float4 x = *(const float4*)&X[(size_t)s * H_DIM + (lane << 2)];
            acc.x += x.x; acc.y += x.y; acc.z += x.z; acc.w += x.w;
        }
    }
    float ir = inv_r[node];
    float4 o;
    o.x = selu_f(acc.x * ir);
    o.y = selu_f(acc.y * ir);
    o.z = selu_f(acc.z * ir);
    o.w = selu_f(acc.w * ir);
    *(float4*)&out_emb[(size_t)node * H_DIM + (lane << 2)] = o;
}

__global__ __launch_bounds__(256) void k_agg2(
    const float* __restrict__ X, const int* __restrict__ csr_send,
    const int* __restrict__ row_ptr, const float* __restrict__ inv_r,
    const float* __restrict__ v, float* __restrict__ out) {
    int node = blockIdx.x * 4 + (threadIdx.x >> 6);
    int lane = threadIdx.x & 63;
    int beg = row_ptr[node], end = row_ptr[node + 1];
    float4 acc = {0.f, 0.f, 0.f, 0.f};
    for (int b = beg; b < end; b += 64) {
        int n = min(64, end - b);
        int myS = (lane < n) ? csr_send[b + lane] : 0x7FFFFFFF;
        myS = wave_sort64(myS, lane);
        for (int i = 0; i < n; ++i) {
            int s = __shfl(myS, i);
            float4 x = *(const float4*)&X[(size_t)s * H_DIM + (lane << 2)];
            acc.x += x.x; acc.y += x.y; acc.z += x.z; acc.w += x.w;
        }
    }
    float ir = inv_r[node];
    float4 vv = *(const float4*)&v[lane << 2];
    float d = selu_f(acc.x * ir) * vv.x + selu_f(acc.y * ir) * vv.y
            + selu_f(acc.z * ir) * vv.z + selu_f(acc.w * ir) * vv.w;
    #pragma unroll
    for (int off = 32; off; off >>= 1) d += __shfl_down(d, off);
    if (lane == 0) out[node] = d;
}

__global__ __launch_bounds__(256) void k_colsum(const float* __restrict__ nodes1,
                                                float* __restrict__ colsum) {
    int t = threadIdx.x;
    size_t r0 = (size_t)blockIdx.x * 64;
    float s = 0.f;
    for (int r = 0; r < 64; ++r) s += nodes1[(r0 + r) * H_DIM + t];
    atomicAdd(&colsum[t], s);
}

__global__ void k_summary_v(const float* __restrict__ colsum, const float* __restrict__ Wb,
                            float* __restrict__ v) {
    __shared__ float s_sum[H_DIM];
    int t = threadIdx.x;
    float m = colsum[t] * (1.f / (float)N_NODES);
    s_sum[t] = 1.f / (1.f + expf(-m));
    __syncthreads();
    float acc = 0.f;
    for (int j = 0; j < H_DIM; ++j) acc += Wb[t * H_DIM + j] * s_sum[j];
    v[t] = acc;
}

__global__ __launch_bounds__(256) void k_normrow(
    float* __restrict__ emb, const float* __restrict__ v,
    float* __restrict__ logits, float* __restrict__ e2) {
    int row = blockIdx.x * 4 + (threadIdx.x >> 6);
    int lane = threadIdx.x & 63;
    float4 a = *(float4*)&emb[(size_t)row * H_DIM + (lane << 2)];
    float4 vv = *(const float4*)&v[lane << 2];
    float d = a.x * vv.x + a.y * vv.y + a.z * vv.z + a.w * vv.w;
    float ss = a.x * a.x + a.y * a.y + a.z * a.z + a.w * a.w;
    #pragma unroll
    for (int off = 32; off; off >>= 1) {
        d += __shfl_xor(d, off);
        ss += __shfl_xor(ss, off);
    }
    if (lane == 0) logits[row] = d;
    float inv = 1.f / sqrtf(ss);
    a.x *= inv; a.y *= inv; a.z *= inv; a.w *= inv;
    *(float4*)&emb[(size_t)row * H_DIM + (lane << 2)] = a;
    float s2 = a.x * a.x + a.y * a.y + a.z * a.z + a.w * a.w;
    #pragma unroll
    for (int off = 32; off; off >>= 1) s2 += __shfl_xor(s2, off);
    if (lane == 0) e2[row] = s2;
}

__global__ __launch_bounds__(256) void k_c2(const float* __restrict__ centers,
                                            float* __restrict__ c2) {
    int row = blockIdx.x * 4 + (threadIdx.x >> 6);
    int lane = threadIdx.x & 63;
    float4 a = *(const float4*)&centers[(size_t)row * H_DIM + (lane << 2)];
    float ss = a.x * a.x + a.y * a.y + a.z * a.z + a.w * a.w;
    #pragma unroll
    for (int off = 32; off; off >>= 1) ss += __shfl_xor(ss, off);
    if (lane == 0) c2[row] = ss;
}

__global__ __launch_bounds__(256) void k_loss(const unsigned* __restrict__ node_min,
                                              double* __restrict__ acc) {
    int i = blockIdx.x * 256 + threadIdx.x;
    float s = __uint_as_float(node_min[i]);
    #pragma unroll
    for (int off = 32; off; off >>= 1) s += __shfl_down(s, off);
    __shared__ float ws[4];
    int lane = threadIdx.x & 63, w = threadIdx.x >> 6;
    if (lane == 0) ws[w] = s;
    __syncthreads();
    if (threadIdx.x == 0) {
        float tot = ws[0] + ws[1] + ws[2] + ws[3];
        atomicAdd(acc, (double)tot);
    }
}

__global__ void k_finalize(const unsigned long long* __restrict__ center_min,
                           const double* __restrict__ loss_acc,
                           float* __restrict__ rep_out, float* __restrict__ loss_out) {
    int t = blockIdx.x * 256 + threadIdx.x;
    if (t < R_REPS) rep_out[t] = (float)(unsigned)(center_min[t] & 0xFFFFFFFFull);
    if (t == 0) *loss_out = (float)(*loss_acc);
}

extern "C" void kernel_launch(void* const* d_in, const int* in_sizes, int n_in,
                              void* d_out, int out_size, void* d_ws, size_t ws_size,
                              hipStream_t stream) {
    const float* nodes   = (const float*)d_in[0];
    const float* c_nodes = (const float*)d_in[1];
    const int* senders   = (const int*)d_in[2];
    const int* receivers = (const int*)d_in[3];
    const float* W       = (const float*)d_in[4];
    const float* bias    = (const float*)d_in[5];
    const float* Wb      = (const float*)d_in[6];
    const float* centers = (const float*)d_in[7];

    float* out = (float*)d_out;
    float* out_emb    = out;
    float* out_cent   = out + (size_t)N_NODES * H_DIM;
    float* out_rep    = out_cent + (size_t)R_REPS * H_DIM;
    float* out_loss   = out_rep + R_REPS;
    float* out_logits = out_loss + 1;

    char* wp = (char*)d_ws;
    unsigned long long* center_min = (unsigned long long*)wp; wp += (size_t)R_REPS * 8;
    double* loss_acc = (double*)wp;             wp += 8;
    float* X = (float*)wp;                      wp += (size_t)N_NODES * H_DIM * 4;
    int* csr_send = (int*)wp;                   wp += (size_t)E_EDGES * 4;
    int* row_ptr = (int*)wp;                    wp += (size_t)(N_NODES + 2) * 4;
    int* cursor = (int*)wp;                     wp += (size_t)N_NODES * 4;
    int* cnt_s = (int*)wp;                      wp += (size_t)N_NODES * 4;
    int* cnt_r = (int*)wp;                      wp += (size_t)N_NODES * 4;
    float* inv_s = (float*)wp;                  wp += (size_t)N_NODES * 4;
    float* inv_r = (float*)wp;                  wp += (size_t)N_NODES * 4;
    float* colsum = (float*)wp;                 wp += (size_t)H_DIM * 4;
    float* v = (float*)wp;                      wp += (size_t)H_DIM * 4;
    float* e2 = (float*)wp;                     wp += (size_t)N_NODES * 4;
    float* c2 = (float*)wp;                     wp += (size_t)R_REPS * 4;
    unsigned* node_min = (unsigned*)wp;         wp += (size_t)N_NODES * 4;
    _Float16* WhiT = (_Float16*)wp;             wp += (size_t)H_DIM * F_DIM * 2;
    _Float16* WloT = (_Float16*)wp;             wp += (size_t)H_DIM * F_DIM * 2;

    k_init<<<N_NODES / 256, 256, 0, stream>>>(cnt_s, cnt_r, colsum, node_min, center_min, loss_acc);
    k_degree<<<E_EDGES / 256, 256, 0, stream>>>(senders, receivers, cnt_s, cnt_r);
    k_invsqrt<<<N_NODES / 256, 256, 0, stream>>>(cnt_s, cnt_r, inv_s, inv_r);
    k_scan<<<1, 1024, 0, stream>>>(cnt_r, row_ptr, cursor);
    k_fill<<<E_EDGES / 256, 256, 0, stream>>>(senders, receivers, cursor, csr_send);
    k_splitWT<<<(F_DIM * H_DIM) / 256, 256, 0, stream>>>(W, WhiT, WloT);

    dim3 gg(N_NODES / 128, H_DIM / 128);
    // GCN1
    k_gemm_mfma<<<gg, 256, 0, stream>>>(nodes, WhiT, WloT, bias, inv_s, X, F_DIM);
    k_agg1<<<N_NODES / 4, 256, 0, stream>>>(X, csr_send, row_ptr, inv_r, out_emb);

    k_colsum<<<N_NODES / 64, 256, 0, stream>>>(out_emb, colsum);
    k_summary_v<<<1, 256, 0, stream>>>(colsum, Wb, v);
    k_normrow<<<N_NODES / 4, 256, 0, stream>>>(out_emb, v, out_logits, e2);
    k_c2<<<R_REPS / 4, 256, 0, stream>>>(centers, c2);

    dim3 gc(N_NODES / 128, R_REPS / 128);
    k_cluster_mfma<<<gc, 256, 0, stream>>>(out_emb, centers, e2, c2, node_min, center_min);
    k_loss<<<N_NODES / 256, 256, 0, stream>>>(node_min, loss_acc);
    k_finalize<<<2, 256, 0, stream>>>(center_min, loss_acc, out_rep, out_loss);
    hipMemcpyAsync(out_cent, centers, (size_t)R_REPS * H_DIM * 4, hipMemcpyDeviceToDevice, stream);

    // GCN2 (reuse X; nodes2 never materialized)
    k_gemm_mfma<<<gg, 256, 0, stream>>>(c_nodes, WhiT, WloT, bias, inv_s, X, F_DIM);
    k_agg2<<<N_NODES / 4, 256, 0, stream>>>(X, csr_send, row_ptr, inv_r, v, out_logits + N_NODES);
}